// Round 1
// baseline (862.214 us; speedup 1.0000x reference)
//
#include <hip/hip_runtime.h>
#include <math.h>

#define T_SEQ 1024
#define C_DIM 1024
#define NB    4
#define NH    16
#define HD    64
#define C3    3072

// ---------------------------------------------------------------------------
// LayerNorm: one block per row, 256 threads, row length 1024 (4 floats/thread)
// Works in-place (values held in regs between read and write).
// ---------------------------------------------------------------------------
__global__ __launch_bounds__(256) void ln_kernel(const float* __restrict__ in,
                                                 float* __restrict__ out,
                                                 const float* __restrict__ g,
                                                 const float* __restrict__ beta,
                                                 int stride) {
    const int row = blockIdx.x;
    const float* x = in + (size_t)row * stride;
    float* y = out + (size_t)row * stride;
    const int t = threadIdx.x;

    float4 v = *(const float4*)&x[t * 4];
    float s  = v.x + v.y + v.z + v.w;
    float ss = v.x * v.x + v.y * v.y + v.z * v.z + v.w * v.w;
    #pragma unroll
    for (int m = 1; m < 64; m <<= 1) {
        s  += __shfl_xor(s, m);
        ss += __shfl_xor(ss, m);
    }
    __shared__ float red[8];
    const int wave = t >> 6, lane = t & 63;
    if (lane == 0) { red[wave * 2] = s; red[wave * 2 + 1] = ss; }
    __syncthreads();
    s  = red[0] + red[2] + red[4] + red[6];
    ss = red[1] + red[3] + red[5] + red[7];

    const float mu   = s * (1.0f / 1024.0f);
    const float var  = ss * (1.0f / 1024.0f) - mu * mu;
    const float rstd = rsqrtf(var + 1e-5f);

    float4 gg = *(const float4*)&g[t * 4];
    float4 bb = *(const float4*)&beta[t * 4];
    float4 o;
    o.x = (v.x - mu) * rstd * gg.x + bb.x;
    o.y = (v.y - mu) * rstd * gg.y + bb.y;
    o.z = (v.z - mu) * rstd * gg.z + bb.z;
    o.w = (v.w - mu) * rstd * gg.w + bb.w;
    *(float4*)&y[t * 4] = o;
}

// ---------------------------------------------------------------------------
// fp32 GEMM + bias: C[M][N] = A[M][K] @ W[K][N] + bias[N]
// Tile BMx128x16, 256 threads (16x16), per-thread (BM/16)x8 microtile.
// Microtile columns split as {tx*4, 64+tx*4} so all ds_read_b128 are <=2-way.
// ---------------------------------------------------------------------------
template <int BM>
__global__ __launch_bounds__(256) void gemm_bias(const float* __restrict__ A,
                                                 const float* __restrict__ W,
                                                 const float* __restrict__ bias,
                                                 float* __restrict__ C,
                                                 int M, int N, int K) {
    constexpr int BN = 128, BK = 16;
    constexpr int RH = BM / 64;  // row-halves per thread (2 for BM=128, 1 for BM=64)

    __shared__ __align__(16) float As[BK][BM];  // transposed A tile: As[k][m]
    __shared__ __align__(16) float Bs[BK][BN];  // natural B tile:   Bs[k][n]

    const int t  = threadIdx.x;
    const int tx = t & 15, ty = t >> 4;
    const int bn = blockIdx.x * BN;
    const int bm = blockIdx.y * BM;

    const float* Ap = A + (size_t)bm * K;
    const float* Bp = W + bn;

    float acc[RH * 4][8];
    #pragma unroll
    for (int i = 0; i < RH * 4; ++i)
        #pragma unroll
        for (int j = 0; j < 8; ++j) acc[i][j] = 0.0f;

    float4 aR[RH], bR[2];

    auto loadAB = [&](int k0) {
        #pragma unroll
        for (int i = 0; i < RH; ++i) {
            int s = t + 256 * i;
            int r = s >> 2, kg = s & 3;
            aR[i] = *(const float4*)&Ap[(size_t)r * K + k0 + kg * 4];
        }
        #pragma unroll
        for (int i = 0; i < 2; ++i) {
            int s = t + 256 * i;
            int kr = s >> 5, ng = s & 31;
            bR[i] = *(const float4*)&Bp[(size_t)(k0 + kr) * N + ng * 4];
        }
    };

    loadAB(0);
    for (int k0 = 0; k0 < K; k0 += BK) {
        __syncthreads();
        #pragma unroll
        for (int i = 0; i < RH; ++i) {
            int s = t + 256 * i;
            int r = s >> 2, kg = s & 3;
            As[kg * 4 + 0][r] = aR[i].x;
            As[kg * 4 + 1][r] = aR[i].y;
            As[kg * 4 + 2][r] = aR[i].z;
            As[kg * 4 + 3][r] = aR[i].w;
        }
        #pragma unroll
        for (int i = 0; i < 2; ++i) {
            int s = t + 256 * i;
            int kr = s >> 5, ng = s & 31;
            *(float4*)&Bs[kr][ng * 4] = bR[i];
        }
        __syncthreads();
        if (k0 + BK < K) loadAB(k0 + BK);  // prefetch next tile (overlaps compute)

        #pragma unroll
        for (int kk = 0; kk < BK; ++kk) {
            float av[RH * 4], bv[8];
            #pragma unroll
            for (int hh = 0; hh < RH; ++hh) {
                float4 a = *(const float4*)&As[kk][hh * 64 + ty * 4];
                av[hh * 4 + 0] = a.x; av[hh * 4 + 1] = a.y;
                av[hh * 4 + 2] = a.z; av[hh * 4 + 3] = a.w;
            }
            float4 b0 = *(const float4*)&Bs[kk][tx * 4];
            float4 b1 = *(const float4*)&Bs[kk][64 + tx * 4];
            bv[0] = b0.x; bv[1] = b0.y; bv[2] = b0.z; bv[3] = b0.w;
            bv[4] = b1.x; bv[5] = b1.y; bv[6] = b1.z; bv[7] = b1.w;
            #pragma unroll
            for (int i = 0; i < RH * 4; ++i)
                #pragma unroll
                for (int j = 0; j < 8; ++j) acc[i][j] += av[i] * bv[j];
        }
    }

    // epilogue: add bias, store
    #pragma unroll
    for (int hh = 0; hh < RH; ++hh) {
        #pragma unroll
        for (int i = 0; i < 4; ++i) {
            int row = bm + hh * 64 + ty * 4 + i;
            #pragma unroll
            for (int jh = 0; jh < 2; ++jh) {
                int col = bn + jh * 64 + tx * 4;
                float4 o;
                o.x = acc[hh * 4 + i][jh * 4 + 0] + bias[col + 0];
                o.y = acc[hh * 4 + i][jh * 4 + 1] + bias[col + 1];
                o.z = acc[hh * 4 + i][jh * 4 + 2] + bias[col + 2];
                o.w = acc[hh * 4 + i][jh * 4 + 3] + bias[col + 3];
                *(float4*)&C[(size_t)row * N + col] = o;
            }
        }
    }
}

// ---------------------------------------------------------------------------
// Flash attention, fp32. One block per (b, h, q-tile of 64). 256 threads
// (16x16), 4x4 microtiles for both QK^T and PV GEMMs. Online softmax.
// Q pre-scaled by 1/sqrt(D) at staging. Q/K staged transposed [d][r] (pad 68),
// V natural [kk][d], P transposed [kk][r] for the PV A-operand.
// ---------------------------------------------------------------------------
__global__ __launch_bounds__(256) void attn_kernel(const float* __restrict__ qkv,
                                                   float* __restrict__ out) {
    const int bid = blockIdx.x;
    const int qt = bid & 15;          // q-tile
    const int bh = bid >> 4;
    const int h  = bh & 15;
    const int b  = bh >> 4;
    const int qbase = qt * 64;

    const float* qptr = qkv + (size_t)(b * T_SEQ) * C3 + h * HD;
    const float* kptr = qptr + 1024;
    const float* vptr = qptr + 2048;

    __shared__ __align__(16) float Qs[64][68];  // [d][r]
    __shared__ __align__(16) float Ks[64][68];  // [d][kk]
    __shared__ __align__(16) float Ps[64][68];  // [kk][r]
    __shared__ __align__(16) float Vs[64][64];  // [kk][d]

    const int t  = threadIdx.x;
    const int tx = t & 15, ty = t >> 4;

    // stage Q (scaled), transposed
    #pragma unroll
    for (int i = 0; i < 4; ++i) {
        int s = t + 256 * i;
        int r = s >> 4, dg = s & 15;
        float4 v = *(const float4*)&qptr[(size_t)(qbase + r) * C3 + dg * 4];
        Qs[dg * 4 + 0][r] = v.x * 0.125f;
        Qs[dg * 4 + 1][r] = v.y * 0.125f;
        Qs[dg * 4 + 2][r] = v.z * 0.125f;
        Qs[dg * 4 + 3][r] = v.w * 0.125f;
    }

    float m_[4], l_[4], o_[4][4];
    #pragma unroll
    for (int i = 0; i < 4; ++i) {
        m_[i] = -INFINITY; l_[i] = 0.0f;
        #pragma unroll
        for (int j = 0; j < 4; ++j) o_[i][j] = 0.0f;
    }

    for (int kt = 0; kt < 16; ++kt) {
        const int kb = kt * 64;
        __syncthreads();  // previous PV done (and Q staged, first iter)
        #pragma unroll
        for (int i = 0; i < 4; ++i) {
            int s = t + 256 * i;
            int r = s >> 4, dg = s & 15;
            float4 kv = *(const float4*)&kptr[(size_t)(kb + r) * C3 + dg * 4];
            Ks[dg * 4 + 0][r] = kv.x;
            Ks[dg * 4 + 1][r] = kv.y;
            Ks[dg * 4 + 2][r] = kv.z;
            Ks[dg * 4 + 3][r] = kv.w;
            float4 vv = *(const float4*)&vptr[(size_t)(kb + r) * C3 + dg * 4];
            *(float4*)&Vs[r][dg * 4] = vv;
        }
        __syncthreads();

        // S = Q K^T (scaled)
        float sacc[4][4];
        #pragma unroll
        for (int i = 0; i < 4; ++i)
            #pragma unroll
            for (int j = 0; j < 4; ++j) sacc[i][j] = 0.0f;

        #pragma unroll 8
        for (int d = 0; d < 64; ++d) {
            float4 qa = *(const float4*)&Qs[d][ty * 4];
            float4 kb4 = *(const float4*)&Ks[d][tx * 4];
            float qv[4] = {qa.x, qa.y, qa.z, qa.w};
            float kv[4] = {kb4.x, kb4.y, kb4.z, kb4.w};
            #pragma unroll
            for (int i = 0; i < 4; ++i)
                #pragma unroll
                for (int j = 0; j < 4; ++j) sacc[i][j] += qv[i] * kv[j];
        }

        // online softmax update (row stats shared across the 16 tx lanes)
        #pragma unroll
        for (int i = 0; i < 4; ++i) {
            float rm = fmaxf(fmaxf(sacc[i][0], sacc[i][1]),
                             fmaxf(sacc[i][2], sacc[i][3]));
            rm = fmaxf(rm, __shfl_xor(rm, 1));
            rm = fmaxf(rm, __shfl_xor(rm, 2));
            rm = fmaxf(rm, __shfl_xor(rm, 4));
            rm = fmaxf(rm, __shfl_xor(rm, 8));
            const float mnew = fmaxf(m_[i], rm);
            const float f = __expf(m_[i] - mnew);
            float p[4], rs = 0.0f;
            #pragma unroll
            for (int j = 0; j < 4; ++j) {
                p[j] = __expf(sacc[i][j] - mnew);
                rs += p[j];
            }
            rs += __shfl_xor(rs, 1);
            rs += __shfl_xor(rs, 2);
            rs += __shfl_xor(rs, 4);
            rs += __shfl_xor(rs, 8);
            l_[i] = l_[i] * f + rs;
            m_[i] = mnew;
            #pragma unroll
            for (int j = 0; j < 4; ++j) {
                o_[i][j] *= f;
                Ps[tx * 4 + j][ty * 4 + i] = p[j];
            }
        }
        __syncthreads();

        // O += P V
        #pragma unroll 8
        for (int kk = 0; kk < 64; ++kk) {
            float4 pa = *(const float4*)&Ps[kk][ty * 4];
            float4 vb = *(const float4*)&Vs[kk][tx * 4];
            float pv[4] = {pa.x, pa.y, pa.z, pa.w};
            float vv[4] = {vb.x, vb.y, vb.z, vb.w};
            #pragma unroll
            for (int i = 0; i < 4; ++i)
                #pragma unroll
                for (int j = 0; j < 4; ++j) o_[i][j] += pv[i] * vv[j];
        }
    }

    // epilogue: normalize, store to [B,T,C] layout
    #pragma unroll
    for (int i = 0; i < 4; ++i) {
        const float inv = 1.0f / l_[i];
        float4 o;
        o.x = o_[i][0] * inv;
        o.y = o_[i][1] * inv;
        o.z = o_[i][2] * inv;
        o.w = o_[i][3] * inv;
        *(float4*)&out[(size_t)(b * T_SEQ + qbase + ty * 4 + i) * C_DIM + h * HD + tx * 4] = o;
    }
}

// ---------------------------------------------------------------------------
extern "C" void kernel_launch(void* const* d_in, const int* in_sizes, int n_in,
                              void* d_out, int out_size, void* d_ws, size_t ws_size,
                              hipStream_t stream) {
    const float* x      = (const float*)d_in[0];
    const float* norm_g = (const float*)d_in[1];
    const float* norm_b = (const float*)d_in[2];
    const float* qkv_w  = (const float*)d_in[3];
    const float* qkv_b  = (const float*)d_in[4];
    const float* qln_g  = (const float*)d_in[5];
    const float* qln_b  = (const float*)d_in[6];
    const float* kln_g  = (const float*)d_in[7];
    const float* kln_b  = (const float*)d_in[8];
    const float* proj_w = (const float*)d_in[9];
    const float* proj_b = (const float*)d_in[10];
    float* out = (float*)d_out;

    float* ws  = (float*)d_ws;
    float* xn  = ws;                               // 4096*1024
    float* qkv = xn + (size_t)4096 * 1024;         // 4096*3072
    float* att = qkv + (size_t)4096 * 3072;        // 4096*1024

    const int rows = NB * T_SEQ;  // 4096

    // 1) pre-LN
    ln_kernel<<<rows, 256, 0, stream>>>(x, xn, norm_g, norm_b, C_DIM);
    // 2) QKV GEMM + bias
    gemm_bias<128><<<dim3(C3 / 128, rows / 128), 256, 0, stream>>>(
        xn, qkv_w, qkv_b, qkv, rows, C3, C_DIM);
    // 3) Q/K LayerNorm (in-place, row stride 3072)
    ln_kernel<<<rows, 256, 0, stream>>>(qkv, qkv, qln_g, qln_b, C3);
    ln_kernel<<<rows, 256, 0, stream>>>(qkv + 1024, qkv + 1024, kln_g, kln_b, C3);
    // 4) flash attention
    attn_kernel<<<NB * NH * (T_SEQ / 64), 256, 0, stream>>>(qkv, att);
    // 5) output projection
    gemm_bias<64><<<dim3(C_DIM / 128, rows / 64), 256, 0, stream>>>(
        att, proj_w, proj_b, out, rows, C_DIM, C_DIM);
}

// Round 2
// 526.731 us; speedup vs baseline: 1.6369x; 1.6369x over previous
//
#include <hip/hip_runtime.h>
#include <math.h>

#define T_SEQ 1024
#define C_DIM 1024
#define NB    4
#define NH    16
#define HD    64
#define C3    3072

typedef __attribute__((ext_vector_type(8))) short bf16x8;
typedef __attribute__((ext_vector_type(4))) float f32x4;
typedef unsigned short u16;

// round-to-nearest bf16 (as raw u16 bits)
__device__ inline u16 bf16_rtn(float v) {
    unsigned int u = __float_as_uint(v);
    u += 0x7FFFu + ((u >> 16) & 1u);
    return (u16)(u >> 16);
}
// split fp32 -> hi + lo bf16 (hi = RTN(v), lo = RTN(v - hi)); hi+lo ~ v to 2^-17
__device__ inline void split_bf16(float v, u16& hi, u16& lo) {
    hi = bf16_rtn(v);
    float hif = __uint_as_float(((unsigned int)hi) << 16);
    lo = bf16_rtn(v - hif);
}

// ---------------------------------------------------------------------------
// LayerNorm fp32 (in-place capable), row length 1024, arbitrary row stride.
// ---------------------------------------------------------------------------
__global__ __launch_bounds__(256) void ln_kernel(const float* __restrict__ in,
                                                 float* __restrict__ out,
                                                 const float* __restrict__ g,
                                                 const float* __restrict__ beta,
                                                 int stride) {
    const int row = blockIdx.x;
    const float* x = in + (size_t)row * stride;
    float* y = out + (size_t)row * stride;
    const int t = threadIdx.x;

    float4 v = *(const float4*)&x[t * 4];
    float s  = v.x + v.y + v.z + v.w;
    float ss = v.x * v.x + v.y * v.y + v.z * v.z + v.w * v.w;
    #pragma unroll
    for (int m = 1; m < 64; m <<= 1) {
        s  += __shfl_xor(s, m);
        ss += __shfl_xor(ss, m);
    }
    __shared__ float red[8];
    const int wave = t >> 6, lane = t & 63;
    if (lane == 0) { red[wave * 2] = s; red[wave * 2 + 1] = ss; }
    __syncthreads();
    s  = red[0] + red[2] + red[4] + red[6];
    ss = red[1] + red[3] + red[5] + red[7];

    const float mu   = s * (1.0f / 1024.0f);
    const float var  = ss * (1.0f / 1024.0f) - mu * mu;
    const float rstd = rsqrtf(var + 1e-5f);

    float4 gg = *(const float4*)&g[t * 4];
    float4 bb = *(const float4*)&beta[t * 4];
    float4 o;
    o.x = (v.x - mu) * rstd * gg.x + bb.x;
    o.y = (v.y - mu) * rstd * gg.y + bb.y;
    o.z = (v.z - mu) * rstd * gg.z + bb.z;
    o.w = (v.w - mu) * rstd * gg.w + bb.w;
    *(float4*)&y[t * 4] = o;
}

// ---------------------------------------------------------------------------
// LayerNorm fp32 -> split bf16 hi/lo outputs (row stride 1024 both sides).
// ---------------------------------------------------------------------------
__global__ __launch_bounds__(256) void ln_split_kernel(const float* __restrict__ in,
                                                       u16* __restrict__ oh,
                                                       u16* __restrict__ ol,
                                                       const float* __restrict__ g,
                                                       const float* __restrict__ beta) {
    const int row = blockIdx.x;
    const float* x = in + (size_t)row * 1024;
    const int t = threadIdx.x;

    float4 v = *(const float4*)&x[t * 4];
    float s  = v.x + v.y + v.z + v.w;
    float ss = v.x * v.x + v.y * v.y + v.z * v.z + v.w * v.w;
    #pragma unroll
    for (int m = 1; m < 64; m <<= 1) {
        s  += __shfl_xor(s, m);
        ss += __shfl_xor(ss, m);
    }
    __shared__ float red[8];
    const int wave = t >> 6, lane = t & 63;
    if (lane == 0) { red[wave * 2] = s; red[wave * 2 + 1] = ss; }
    __syncthreads();
    s  = red[0] + red[2] + red[4] + red[6];
    ss = red[1] + red[3] + red[5] + red[7];

    const float mu   = s * (1.0f / 1024.0f);
    const float var  = ss * (1.0f / 1024.0f) - mu * mu;
    const float rstd = rsqrtf(var + 1e-5f);

    float4 gg = *(const float4*)&g[t * 4];
    float4 bb = *(const float4*)&beta[t * 4];
    float o[4];
    o[0] = (v.x - mu) * rstd * gg.x + bb.x;
    o[1] = (v.y - mu) * rstd * gg.y + bb.y;
    o[2] = (v.z - mu) * rstd * gg.z + bb.z;
    o[3] = (v.w - mu) * rstd * gg.w + bb.w;

    ushort4 h4, l4;
    split_bf16(o[0], h4.x, l4.x);
    split_bf16(o[1], h4.y, l4.y);
    split_bf16(o[2], h4.z, l4.z);
    split_bf16(o[3], h4.w, l4.w);
    size_t off = (size_t)row * 1024 + t * 4;
    *(ushort4*)&oh[off] = h4;
    *(ushort4*)&ol[off] = l4;
}

// ---------------------------------------------------------------------------
// Weight split + transpose: W[K][N] fp32 -> Th/Tl[N][K] bf16 (64x64 tiles).
// ---------------------------------------------------------------------------
__global__ __launch_bounds__(256) void wsplit_t(const float* __restrict__ W,
                                                u16* __restrict__ Th,
                                                u16* __restrict__ Tl,
                                                int K, int N) {
    __shared__ float tile[64][69];  // odd-ish pad: strided col reads ~2-way
    const int n0 = blockIdx.x * 64, k0 = blockIdx.y * 64;
    const int t = threadIdx.x;
    #pragma unroll
    for (int i = 0; i < 4; ++i) {
        int idx = t + 256 * i;
        int kr = idx >> 4, nc = (idx & 15) * 4;
        float4 v = *(const float4*)&W[(size_t)(k0 + kr) * N + n0 + nc];
        tile[kr][nc + 0] = v.x; tile[kr][nc + 1] = v.y;
        tile[kr][nc + 2] = v.z; tile[kr][nc + 3] = v.w;
    }
    __syncthreads();
    #pragma unroll
    for (int i = 0; i < 4; ++i) {
        int idx = t + 256 * i;
        int nr = idx >> 4, kc = (idx & 15) * 4;
        ushort4 h4, l4;
        split_bf16(tile[kc + 0][nr], h4.x, l4.x);
        split_bf16(tile[kc + 1][nr], h4.y, l4.y);
        split_bf16(tile[kc + 2][nr], h4.z, l4.z);
        split_bf16(tile[kc + 3][nr], h4.w, l4.w);
        size_t o = (size_t)(n0 + nr) * K + k0 + kc;
        *(ushort4*)&Th[o] = h4;
        *(ushort4*)&Tl[o] = l4;
    }
}

// ---------------------------------------------------------------------------
// Split-bf16 MFMA GEMM: C[M][N] = (Ah+Al)[M][K] @ (Bh+Bl)^T + bias.
// A row-major [M][K] bf16; B stored transposed [N][K] bf16.
// 128x128 tile, BK=32, 4 waves (2x2 of 64x64), 16x16x32 bf16 MFMA,
// 3-product split (hh + lh + hl). global_load_lds staging with chunk-XOR
// swizzle (16B chunk c at phys c^(row&3)) so frag ds_read_b128 are
// conflict-free (each instruction covers a contiguous 1KB of LDS).
// ---------------------------------------------------------------------------
__global__ __launch_bounds__(256) void gemm_mfma_split(
    const u16* __restrict__ Ah, const u16* __restrict__ Al,
    const u16* __restrict__ Bh, const u16* __restrict__ Bl,
    const float* __restrict__ bias, float* __restrict__ C,
    int M, int N, int K) {
    __shared__ u16 sAh[128 * 32], sAl[128 * 32], sBh[128 * 32], sBl[128 * 32];

    const int t    = threadIdx.x;
    const int lane = t & 63;
    const int wid  = t >> 6;
    const int wr   = wid >> 1, wc = wid & 1;

    // XCD-aware block swizzle (nwg % 8 == 0 for all our grids)
    const int nbx = gridDim.x;
    const int nwg = nbx * gridDim.y;
    int bid = blockIdx.y * nbx + blockIdx.x;
    int swz = (bid & 7) * (nwg >> 3) + (bid >> 3);
    const int bn = (swz % nbx) * 128;
    const int bm = (swz / nbx) * 128;

    // staging geometry: lane -> (row-in-16-group, phys chunk)
    const int jr    = lane >> 2;
    const int cphys = lane & 3;
    // fragment geometry
    const int m16 = lane & 15, g8 = lane >> 4;

    f32x4 acc[4][4];
    #pragma unroll
    for (int m = 0; m < 4; ++m)
        #pragma unroll
        for (int n = 0; n < 4; ++n) {
            f32x4 z = {0.0f, 0.0f, 0.0f, 0.0f};
            acc[m][n] = z;
        }

    for (int k0 = 0; k0 < K; k0 += 32) {
        __syncthreads();  // previous iter's frag reads done
        #pragma unroll
        for (int jj = 0; jj < 2; ++jj) {
            const int j = wid * 2 + jj;       // 16-row group (0..7)
            const int r = (j << 4) + jr;      // local tile row (0..127)
            const int cl = cphys ^ (r & 3);   // logical chunk for this phys slot
            const size_t ga = ((size_t)(bm + r) * K + k0 + (cl << 3)) * 2;  // bytes
            const size_t gb = ((size_t)(bn + r) * K + k0 + (cl << 3)) * 2;
            const unsigned ldso = (unsigned)(j << 10);  // wave-uniform LDS byte base
            __builtin_amdgcn_global_load_lds(
                (const __attribute__((address_space(1))) void*)((const char*)Ah + ga),
                (__attribute__((address_space(3))) void*)((char*)sAh + ldso), 16, 0, 0);
            __builtin_amdgcn_global_load_lds(
                (const __attribute__((address_space(1))) void*)((const char*)Al + ga),
                (__attribute__((address_space(3))) void*)((char*)sAl + ldso), 16, 0, 0);
            __builtin_amdgcn_global_load_lds(
                (const __attribute__((address_space(1))) void*)((const char*)Bh + gb),
                (__attribute__((address_space(3))) void*)((char*)sBh + ldso), 16, 0, 0);
            __builtin_amdgcn_global_load_lds(
                (const __attribute__((address_space(1))) void*)((const char*)Bl + gb),
                (__attribute__((address_space(3))) void*)((char*)sBl + ldso), 16, 0, 0);
        }
        __syncthreads();  // compiler drains vmcnt before s_barrier -> tiles ready

        bf16x8 ah[4], al[4], bh[4], bl[4];
        #pragma unroll
        for (int m = 0; m < 4; ++m) {
            const int r = wr * 64 + m * 16 + m16;
            const int off = (r << 5) + ((g8 ^ (m16 & 3)) << 3);
            ah[m] = *(const bf16x8*)&sAh[off];
            al[m] = *(const bf16x8*)&sAl[off];
        }
        #pragma unroll
        for (int n = 0; n < 4; ++n) {
            const int r = wc * 64 + n * 16 + m16;
            const int off = (r << 5) + ((g8 ^ (m16 & 3)) << 3);
            bh[n] = *(const bf16x8*)&sBh[off];
            bl[n] = *(const bf16x8*)&sBl[off];
        }
        #pragma unroll
        for (int m = 0; m < 4; ++m)
            #pragma unroll
            for (int n = 0; n < 4; ++n) {
                acc[m][n] = __builtin_amdgcn_mfma_f32_16x16x32_bf16(ah[m], bh[n], acc[m][n], 0, 0, 0);
                acc[m][n] = __builtin_amdgcn_mfma_f32_16x16x32_bf16(al[m], bh[n], acc[m][n], 0, 0, 0);
                acc[m][n] = __builtin_amdgcn_mfma_f32_16x16x32_bf16(ah[m], bl[n], acc[m][n], 0, 0, 0);
            }
    }

    // epilogue: D row = (lane>>4)*4 + e, col = lane&15 (m89-verified layout)
    #pragma unroll
    for (int m = 0; m < 4; ++m) {
        const int row0 = bm + wr * 64 + m * 16 + (g8 << 2);
        #pragma unroll
        for (int n = 0; n < 4; ++n) {
            const int col = bn + wc * 64 + n * 16 + m16;
            const float bv = bias[col];
            #pragma unroll
            for (int e = 0; e < 4; ++e)
                C[(size_t)(row0 + e) * N + col] = acc[m][n][e] + bv;
        }
    }
}

// ---------------------------------------------------------------------------
// Flash attention, fp32 (unchanged math) — epilogue now writes split bf16.
// ---------------------------------------------------------------------------
__global__ __launch_bounds__(256) void attn_kernel(const float* __restrict__ qkv,
                                                   u16* __restrict__ att_hi,
                                                   u16* __restrict__ att_lo) {
    const int bid = blockIdx.x;
    const int qt = bid & 15;
    const int bh = bid >> 4;
    const int h  = bh & 15;
    const int b  = bh >> 4;
    const int qbase = qt * 64;

    const float* qptr = qkv + (size_t)(b * T_SEQ) * C3 + h * HD;
    const float* kptr = qptr + 1024;
    const float* vptr = qptr + 2048;

    __shared__ __align__(16) float Qs[64][68];
    __shared__ __align__(16) float Ks[64][68];
    __shared__ __align__(16) float Ps[64][68];
    __shared__ __align__(16) float Vs[64][64];

    const int t  = threadIdx.x;
    const int tx = t & 15, ty = t >> 4;

    #pragma unroll
    for (int i = 0; i < 4; ++i) {
        int s = t + 256 * i;
        int r = s >> 4, dg = s & 15;
        float4 v = *(const float4*)&qptr[(size_t)(qbase + r) * C3 + dg * 4];
        Qs[dg * 4 + 0][r] = v.x * 0.125f;
        Qs[dg * 4 + 1][r] = v.y * 0.125f;
        Qs[dg * 4 + 2][r] = v.z * 0.125f;
        Qs[dg * 4 + 3][r] = v.w * 0.125f;
    }

    float m_[4], l_[4], o_[4][4];
    #pragma unroll
    for (int i = 0; i < 4; ++i) {
        m_[i] = -INFINITY; l_[i] = 0.0f;
        #pragma unroll
        for (int j = 0; j < 4; ++j) o_[i][j] = 0.0f;
    }

    for (int kt = 0; kt < 16; ++kt) {
        const int kb = kt * 64;
        __syncthreads();
        #pragma unroll
        for (int i = 0; i < 4; ++i) {
            int s = t + 256 * i;
            int r = s >> 4, dg = s & 15;
            float4 kv = *(const float4*)&kptr[(size_t)(kb + r) * C3 + dg * 4];
            Ks[dg * 4 + 0][r] = kv.x;
            Ks[dg * 4 + 1][r] = kv.y;
            Ks[dg * 4 + 2][r] = kv.z;
            Ks[dg * 4 + 3][r] = kv.w;
            float4 vv = *(const float4*)&vptr[(size_t)(kb + r) * C3 + dg * 4];
            *(float4*)&Vs[r][dg * 4] = vv;
        }
        __syncthreads();

        float sacc[4][4];
        #pragma unroll
        for (int i = 0; i < 4; ++i)
            #pragma unroll
            for (int j = 0; j < 4; ++j) sacc[i][j] = 0.0f;

        #pragma unroll 8
        for (int d = 0; d < 64; ++d) {
            float4 qa  = *(const float4*)&Qs[d][ty * 4];
            float4 kb4 = *(const float4*)&Ks[d][tx * 4];
            float qv[4] = {qa.x, qa.y, qa.z, qa.w};
            float kv[4] = {kb4.x, kb4.y, kb4.z, kb4.w};
            #pragma unroll
            for (int i = 0; i < 4; ++i)
                #pragma unroll
                for (int j = 0; j < 4; ++j) sacc[i][j] += qv[i] * kv[j];
        }

        #pragma unroll
        for (int i = 0; i < 4; ++i) {
            float rm = fmaxf(fmaxf(sacc[i][0], sacc[i][1]),
                             fmaxf(sacc[i][2], sacc[i][3]));
            rm = fmaxf(rm, __shfl_xor(rm, 1));
            rm = fmaxf(rm, __shfl_xor(rm, 2));
            rm = fmaxf(rm, __shfl_xor(rm, 4));
            rm = fmaxf(rm, __shfl_xor(rm, 8));
            const float mnew = fmaxf(m_[i], rm);
            const float f = __expf(m_[i] - mnew);
            float p[4], rs = 0.0f;
            #pragma unroll
            for (int j = 0; j < 4; ++j) {
                p[j] = __expf(sacc[i][j] - mnew);
                rs += p[j];
            }
            rs += __shfl_xor(rs, 1);
            rs += __shfl_xor(rs, 2);
            rs += __shfl_xor(rs, 4);
            rs += __shfl_xor(rs, 8);
            l_[i] = l_[i] * f + rs;
            m_[i] = mnew;
            #pragma unroll
            for (int j = 0; j < 4; ++j) {
                o_[i][j] *= f;
                Ps[tx * 4 + j][ty * 4 + i] = p[j];
            }
        }
        __syncthreads();

        #pragma unroll 8
        for (int kk = 0; kk < 64; ++kk) {
            float4 pa = *(const float4*)&Ps[kk][ty * 4];
            float4 vb = *(const float4*)&Vs[kk][tx * 4];
            float pv[4] = {pa.x, pa.y, pa.z, pa.w};
            float vv[4] = {vb.x, vb.y, vb.z, vb.w};
            #pragma unroll
            for (int i = 0; i < 4; ++i)
                #pragma unroll
                for (int j = 0; j < 4; ++j) o_[i][j] += pv[i] * vv[j];
        }
    }

    #pragma unroll
    for (int i = 0; i < 4; ++i) {
        const float inv = 1.0f / l_[i];
        float o0 = o_[i][0] * inv, o1 = o_[i][1] * inv;
        float o2 = o_[i][2] * inv, o3 = o_[i][3] * inv;
        ushort4 h4, l4;
        split_bf16(o0, h4.x, l4.x);
        split_bf16(o1, h4.y, l4.y);
        split_bf16(o2, h4.z, l4.z);
        split_bf16(o3, h4.w, l4.w);
        size_t off = (size_t)(b * T_SEQ + qbase + ty * 4 + i) * C_DIM + h * HD + tx * 4;
        *(ushort4*)&att_hi[off] = h4;
        *(ushort4*)&att_lo[off] = l4;
    }
}

// ---------------------------------------------------------------------------
extern "C" void kernel_launch(void* const* d_in, const int* in_sizes, int n_in,
                              void* d_out, int out_size, void* d_ws, size_t ws_size,
                              hipStream_t stream) {
    const float* x      = (const float*)d_in[0];
    const float* norm_g = (const float*)d_in[1];
    const float* norm_b = (const float*)d_in[2];
    const float* qkv_w  = (const float*)d_in[3];
    const float* qkv_b  = (const float*)d_in[4];
    const float* qln_g  = (const float*)d_in[5];
    const float* qln_b  = (const float*)d_in[6];
    const float* kln_g  = (const float*)d_in[7];
    const float* kln_b  = (const float*)d_in[8];
    const float* proj_w = (const float*)d_in[9];
    const float* proj_b = (const float*)d_in[10];
    float* out = (float*)d_out;

    // workspace layout (83,886,080 B total — same as round-1 usage)
    char* w = (char*)d_ws;
    float* qkv  = (float*)w;                          // 4096*3072*4 = 50331648
    u16* xn_hi  = (u16*)(w + 50331648);               // 4096*1024*2 =  8388608
    u16* xn_lo  = (u16*)(w + 58720256);               //                8388608
    u16* wq_hi  = (u16*)(w + 67108864);               // 3072*1024*2 =  6291456
    u16* wq_lo  = (u16*)(w + 73400320);               //                6291456
    u16* pw_hi  = (u16*)(w + 79691776);               // 1024*1024*2 =  2097152
    u16* pw_lo  = (u16*)(w + 81788928);               //                2097152
    // att hi/lo reuse xn hi/lo (xn dead after the qkv GEMM)
    u16* att_hi = xn_hi;
    u16* att_lo = xn_lo;

    const int rows = NB * T_SEQ;  // 4096

    // 1) pre-LN -> split bf16
    ln_split_kernel<<<rows, 256, 0, stream>>>(x, xn_hi, xn_lo, norm_g, norm_b);
    // 2) weight split + transpose
    wsplit_t<<<dim3(C3 / 64, C_DIM / 64), 256, 0, stream>>>(qkv_w, wq_hi, wq_lo, C_DIM, C3);
    wsplit_t<<<dim3(C_DIM / 64, C_DIM / 64), 256, 0, stream>>>(proj_w, pw_hi, pw_lo, C_DIM, C_DIM);
    // 3) QKV GEMM (split-bf16 MFMA) -> fp32 qkv
    gemm_mfma_split<<<dim3(C3 / 128, rows / 128), 256, 0, stream>>>(
        xn_hi, xn_lo, wq_hi, wq_lo, qkv_b, qkv, rows, C3, C_DIM);
    // 4) Q/K LayerNorm fp32 in-place (row stride 3072)
    ln_kernel<<<rows, 256, 0, stream>>>(qkv, qkv, qln_g, qln_b, C3);
    ln_kernel<<<rows, 256, 0, stream>>>(qkv + 1024, qkv + 1024, kln_g, kln_b, C3);
    // 5) flash attention (fp32) -> split bf16 att
    attn_kernel<<<NB * NH * (T_SEQ / 64), 256, 0, stream>>>(qkv, att_hi, att_lo);
    // 6) output projection (split-bf16 MFMA) -> fp32 out
    gemm_mfma_split<<<dim3(C_DIM / 128, rows / 128), 256, 0, stream>>>(
        att_hi, att_lo, pw_hi, pw_lo, proj_b, out, rows, C_DIM, C_DIM);
}

// Round 4
// 342.462 us; speedup vs baseline: 2.5177x; 1.5381x over previous
//
#include <hip/hip_runtime.h>
#include <math.h>

#define T_SEQ 1024
#define C_DIM 1024
#define NB    4
#define NH    16
#define HD    64
#define C3    3072

typedef __attribute__((ext_vector_type(8))) short bf16x8;
typedef __attribute__((ext_vector_type(4))) float f32x4;
typedef unsigned short u16;

union B8 { bf16x8 v; u16 u[8]; unsigned d[4]; };

// round-to-nearest bf16 (as raw u16 bits)
__device__ inline u16 bf16_rtn(float v) {
    unsigned int u = __float_as_uint(v);
    u += 0x7FFFu + ((u >> 16) & 1u);
    return (u16)(u >> 16);
}
// split fp32 -> hi + lo bf16 (hi = RTN(v), lo = RTN(v - hi)); hi+lo ~ v to 2^-17
__device__ inline void split_bf16(float v, u16& hi, u16& lo) {
    hi = bf16_rtn(v);
    float hif = __uint_as_float(((unsigned int)hi) << 16);
    lo = bf16_rtn(v - hif);
}

// ---------------------------------------------------------------------------
// LayerNorm fp32 -> split bf16 hi/lo outputs (row stride 1024 both sides).
// ---------------------------------------------------------------------------
__global__ __launch_bounds__(256) void ln_split_kernel(const float* __restrict__ in,
                                                       u16* __restrict__ oh,
                                                       u16* __restrict__ ol,
                                                       const float* __restrict__ g,
                                                       const float* __restrict__ beta) {
    const int row = blockIdx.x;
    const float* x = in + (size_t)row * 1024;
    const int t = threadIdx.x;

    float4 v = *(const float4*)&x[t * 4];
    float s  = v.x + v.y + v.z + v.w;
    float ss = v.x * v.x + v.y * v.y + v.z * v.z + v.w * v.w;
    #pragma unroll
    for (int m = 1; m < 64; m <<= 1) {
        s  += __shfl_xor(s, m);
        ss += __shfl_xor(ss, m);
    }
    __shared__ float red[8];
    const int wave = t >> 6, lane = t & 63;
    if (lane == 0) { red[wave * 2] = s; red[wave * 2 + 1] = ss; }
    __syncthreads();
    s  = red[0] + red[2] + red[4] + red[6];
    ss = red[1] + red[3] + red[5] + red[7];

    const float mu   = s * (1.0f / 1024.0f);
    const float var  = ss * (1.0f / 1024.0f) - mu * mu;
    const float rstd = rsqrtf(var + 1e-5f);

    float4 gg = *(const float4*)&g[t * 4];
    float4 bb = *(const float4*)&beta[t * 4];
    float o[4];
    o[0] = (v.x - mu) * rstd * gg.x + bb.x;
    o[1] = (v.y - mu) * rstd * gg.y + bb.y;
    o[2] = (v.z - mu) * rstd * gg.z + bb.z;
    o[3] = (v.w - mu) * rstd * gg.w + bb.w;

    ushort4 h4, l4;
    split_bf16(o[0], h4.x, l4.x);
    split_bf16(o[1], h4.y, l4.y);
    split_bf16(o[2], h4.z, l4.z);
    split_bf16(o[3], h4.w, l4.w);
    size_t off = (size_t)row * 1024 + t * 4;
    *(ushort4*)&oh[off] = h4;
    *(ushort4*)&ol[off] = l4;
}

// ---------------------------------------------------------------------------
// Fused Q/K LayerNorm, in-place on qkv (row stride 3072).
// blocks 0..4095 -> Q rows; 4096..8191 -> K rows.
// ---------------------------------------------------------------------------
__global__ __launch_bounds__(256) void ln_qk_kernel(float* __restrict__ qkv,
                                                    const float* __restrict__ qg,
                                                    const float* __restrict__ qb,
                                                    const float* __restrict__ kg,
                                                    const float* __restrict__ kb) {
    const int row = blockIdx.x;
    const int isK = row >> 12;
    const int r = row & 4095;
    float* x = qkv + (size_t)r * C3 + (isK ? 1024 : 0);
    const float* g    = isK ? kg : qg;
    const float* beta = isK ? kb : qb;
    const int t = threadIdx.x;

    float4 v = *(const float4*)&x[t * 4];
    float s  = v.x + v.y + v.z + v.w;
    float ss = v.x * v.x + v.y * v.y + v.z * v.z + v.w * v.w;
    #pragma unroll
    for (int m = 1; m < 64; m <<= 1) {
        s  += __shfl_xor(s, m);
        ss += __shfl_xor(ss, m);
    }
    __shared__ float red[8];
    const int wave = t >> 6, lane = t & 63;
    if (lane == 0) { red[wave * 2] = s; red[wave * 2 + 1] = ss; }
    __syncthreads();
    s  = red[0] + red[2] + red[4] + red[6];
    ss = red[1] + red[3] + red[5] + red[7];

    const float mu   = s * (1.0f / 1024.0f);
    const float var  = ss * (1.0f / 1024.0f) - mu * mu;
    const float rstd = rsqrtf(var + 1e-5f);

    float4 gg = *(const float4*)&g[t * 4];
    float4 bb = *(const float4*)&beta[t * 4];
    float4 o;
    o.x = (v.x - mu) * rstd * gg.x + bb.x;
    o.y = (v.y - mu) * rstd * gg.y + bb.y;
    o.z = (v.z - mu) * rstd * gg.z + bb.z;
    o.w = (v.w - mu) * rstd * gg.w + bb.w;
    *(float4*)&x[t * 4] = o;
}

// ---------------------------------------------------------------------------
// Weight split + transpose: W[K][N] fp32 -> Th/Tl[N][K] bf16 (64x64 tiles).
// ---------------------------------------------------------------------------
__global__ __launch_bounds__(256) void wsplit_t(const float* __restrict__ W,
                                                u16* __restrict__ Th,
                                                u16* __restrict__ Tl,
                                                int K, int N) {
    __shared__ float tile[64][69];
    const int n0 = blockIdx.x * 64, k0 = blockIdx.y * 64;
    const int t = threadIdx.x;
    #pragma unroll
    for (int i = 0; i < 4; ++i) {
        int idx = t + 256 * i;
        int kr = idx >> 4, nc = (idx & 15) * 4;
        float4 v = *(const float4*)&W[(size_t)(k0 + kr) * N + n0 + nc];
        tile[kr][nc + 0] = v.x; tile[kr][nc + 1] = v.y;
        tile[kr][nc + 2] = v.z; tile[kr][nc + 3] = v.w;
    }
    __syncthreads();
    #pragma unroll
    for (int i = 0; i < 4; ++i) {
        int idx = t + 256 * i;
        int nr = idx >> 4, kc = (idx & 15) * 4;
        ushort4 h4, l4;
        split_bf16(tile[kc + 0][nr], h4.x, l4.x);
        split_bf16(tile[kc + 1][nr], h4.y, l4.y);
        split_bf16(tile[kc + 2][nr], h4.z, l4.z);
        split_bf16(tile[kc + 3][nr], h4.w, l4.w);
        size_t o = (size_t)(n0 + nr) * K + k0 + kc;
        *(ushort4*)&Th[o] = h4;
        *(ushort4*)&Tl[o] = l4;
    }
}

// ---------------------------------------------------------------------------
// Split-bf16 MFMA GEMM: C = (Ah+Al) @ (Bh+Bl)^T + bias
// ---------------------------------------------------------------------------
__global__ __launch_bounds__(256) void gemm_mfma_split(
    const u16* __restrict__ Ah, const u16* __restrict__ Al,
    const u16* __restrict__ Bh, const u16* __restrict__ Bl,
    const float* __restrict__ bias, float* __restrict__ C,
    int M, int N, int K) {
    __shared__ u16 sAh[128 * 32], sAl[128 * 32], sBh[128 * 32], sBl[128 * 32];

    const int t    = threadIdx.x;
    const int lane = t & 63;
    const int wid  = t >> 6;
    const int wr   = wid >> 1, wc = wid & 1;

    const int nbx = gridDim.x;
    const int nwg = nbx * gridDim.y;
    int bid = blockIdx.y * nbx + blockIdx.x;
    int swz = (bid & 7) * (nwg >> 3) + (bid >> 3);
    const int bn = (swz % nbx) * 128;
    const int bm = (swz / nbx) * 128;

    const int jr    = lane >> 2;
    const int cphys = lane & 3;
    const int m16 = lane & 15, g8 = lane >> 4;

    f32x4 acc[4][4];
    #pragma unroll
    for (int m = 0; m < 4; ++m)
        #pragma unroll
        for (int n = 0; n < 4; ++n) {
            f32x4 z = {0.0f, 0.0f, 0.0f, 0.0f};
            acc[m][n] = z;
        }

    for (int k0 = 0; k0 < K; k0 += 32) {
        __syncthreads();
        #pragma unroll
        for (int jj = 0; jj < 2; ++jj) {
            const int j = wid * 2 + jj;
            const int r = (j << 4) + jr;
            const int cl = cphys ^ (r & 3);
            const size_t ga = ((size_t)(bm + r) * K + k0 + (cl << 3)) * 2;
            const size_t gb = ((size_t)(bn + r) * K + k0 + (cl << 3)) * 2;
            const unsigned ldso = (unsigned)(j << 10);
            __builtin_amdgcn_global_load_lds(
                (const __attribute__((address_space(1))) void*)((const char*)Ah + ga),
                (__attribute__((address_space(3))) void*)((char*)sAh + ldso), 16, 0, 0);
            __builtin_amdgcn_global_load_lds(
                (const __attribute__((address_space(1))) void*)((const char*)Al + ga),
                (__attribute__((address_space(3))) void*)((char*)sAl + ldso), 16, 0, 0);
            __builtin_amdgcn_global_load_lds(
                (const __attribute__((address_space(1))) void*)((const char*)Bh + gb),
                (__attribute__((address_space(3))) void*)((char*)sBh + ldso), 16, 0, 0);
            __builtin_amdgcn_global_load_lds(
                (const __attribute__((address_space(1))) void*)((const char*)Bl + gb),
                (__attribute__((address_space(3))) void*)((char*)sBl + ldso), 16, 0, 0);
        }
        __syncthreads();

        bf16x8 ah[4], al[4], bh[4], bl[4];
        #pragma unroll
        for (int m = 0; m < 4; ++m) {
            const int r = wr * 64 + m * 16 + m16;
            const int off = (r << 5) + ((g8 ^ (m16 & 3)) << 3);
            ah[m] = *(const bf16x8*)&sAh[off];
            al[m] = *(const bf16x8*)&sAl[off];
        }
        #pragma unroll
        for (int n = 0; n < 4; ++n) {
            const int r = wc * 64 + n * 16 + m16;
            const int off = (r << 5) + ((g8 ^ (m16 & 3)) << 3);
            bh[n] = *(const bf16x8*)&sBh[off];
            bl[n] = *(const bf16x8*)&sBl[off];
        }
        #pragma unroll
        for (int m = 0; m < 4; ++m)
            #pragma unroll
            for (int n = 0; n < 4; ++n) {
                acc[m][n] = __builtin_amdgcn_mfma_f32_16x16x32_bf16(ah[m], bh[n], acc[m][n], 0, 0, 0);
                acc[m][n] = __builtin_amdgcn_mfma_f32_16x16x32_bf16(al[m], bh[n], acc[m][n], 0, 0, 0);
                acc[m][n] = __builtin_amdgcn_mfma_f32_16x16x32_bf16(ah[m], bl[n], acc[m][n], 0, 0, 0);
            }
    }

    #pragma unroll
    for (int m = 0; m < 4; ++m) {
        const int row0 = bm + wr * 64 + m * 16 + (g8 << 2);
        #pragma unroll
        for (int n = 0; n < 4; ++n) {
            const int col = bn + wc * 64 + n * 16 + m16;
            const float bv = bias[col];
            #pragma unroll
            for (int e = 0; e < 4; ++e)
                C[(size_t)(row0 + e) * N + col] = acc[m][n][e] + bv;
        }
    }
}

// ---------------------------------------------------------------------------
// MFMA flash attention, split-bf16 everywhere (fp32-grade accuracy).
// Block = 64 q-rows (4 waves x 16 q), KV tiles of 64 keys, 16x16x32 bf16 MFMA.
// S^T = mfma(K, Q): lane&15 = q -> per-lane softmax (2 shfl_xor for reduce).
// O^T = mfma(Vt, P): output col = q = lane&15 -> no cross-lane rescale.
// All LDS tiles [row][64] bf16 with 16B-chunk XOR swizzle (chunk ^ (row&7)).
// ---------------------------------------------------------------------------
__global__ __launch_bounds__(256) void attn_mfma(const float* __restrict__ qkv,
                                                 u16* __restrict__ att_hi,
                                                 u16* __restrict__ att_lo) {
    __shared__ __align__(16) u16 SM[24576];  // 48 KB
    u16* Kh = SM;              // [64 k][64 d]
    u16* Kl = SM + 4096;
    u16* Vh = SM + 8192;       // transposed [64 d][64 k]
    u16* Vl = SM + 12288;
    u16* Ph = SM + 16384;      // 4 waves x [16 q][64 k]  (reused for O at end)
    u16* Pl = SM + 20480;

    const int t    = threadIdx.x;
    const int lane = t & 63;
    const int wv   = t >> 6;
    const int m16  = lane & 15, g8 = lane >> 4;

    // XCD-chunked swizzle: 1024 blocks, 128 consecutive works per XCD
    const int bid  = blockIdx.x;
    const int work = (bid & 7) * 128 + (bid >> 3);
    const int qt = work & 15;
    const int bh = work >> 4;
    const int h  = bh & 15;
    const int b  = bh >> 4;
    const int q0 = qt * 64;

    const float* qp = qkv + (size_t)b * T_SEQ * C3 + h * HD;
    const float* kp = qp + 1024;
    const float* vp = qp + 2048;

    // --- Q fragments in registers (scaled by 1/sqrt(D), split hi/lo) ---
    bf16x8 qh[2], ql[2];
    {
        const float* qrow = qp + (size_t)(q0 + wv * 16 + m16) * C3;
        #pragma unroll
        for (int ds = 0; ds < 2; ++ds) {
            float4 a = *(const float4*)&qrow[ds * 32 + g8 * 8];
            float4 c = *(const float4*)&qrow[ds * 32 + g8 * 8 + 4];
            float q8[8] = {a.x, a.y, a.z, a.w, c.x, c.y, c.z, c.w};
            B8 hh, ll;
            #pragma unroll
            for (int j = 0; j < 8; ++j) {
                float v = q8[j] * 0.125f;
                u16 hi, lo;
                split_bf16(v, hi, lo);
                hh.u[j] = hi; ll.u[j] = lo;
            }
            qh[ds] = hh.v; ql[ds] = ll.v;
        }
    }

    float kreg[16], vreg[16];

    auto load_tile = [&](int kt) {
        const int kb = kt * 64;
        #pragma unroll
        for (int i = 0; i < 2; ++i) {
            int c = t + 256 * i;
            int kr = c >> 3, dg8 = c & 7;
            float4 a = *(const float4*)&kp[(size_t)(kb + kr) * C3 + dg8 * 8];
            float4 d = *(const float4*)&kp[(size_t)(kb + kr) * C3 + dg8 * 8 + 4];
            kreg[i * 8 + 0] = a.x; kreg[i * 8 + 1] = a.y;
            kreg[i * 8 + 2] = a.z; kreg[i * 8 + 3] = a.w;
            kreg[i * 8 + 4] = d.x; kreg[i * 8 + 5] = d.y;
            kreg[i * 8 + 6] = d.z; kreg[i * 8 + 7] = d.w;
        }
        #pragma unroll
        for (int i = 0; i < 16; ++i)
            vreg[i] = vp[(size_t)(kb + wv * 16 + i) * C3 + lane];
    };

    auto write_tile = [&]() {
        #pragma unroll
        for (int i = 0; i < 2; ++i) {
            int c = t + 256 * i;
            int kr = c >> 3, dg8 = c & 7;
            B8 hh, ll;
            #pragma unroll
            for (int j = 0; j < 8; ++j) split_bf16(kreg[i * 8 + j], hh.u[j], ll.u[j]);
            int idx = kr * 64 + ((dg8 ^ (kr & 7)) << 3);
            *(bf16x8*)&Kh[idx] = hh.v;
            *(bf16x8*)&Kl[idx] = ll.v;
        }
        B8 vh0, vl0, vh1, vl1;
        #pragma unroll
        for (int i = 0; i < 8; ++i)  split_bf16(vreg[i],     vh0.u[i], vl0.u[i]);
        #pragma unroll
        for (int i = 0; i < 8; ++i)  split_bf16(vreg[i + 8], vh1.u[i], vl1.u[i]);
        const int vb = lane * 64;
        *(bf16x8*)&Vh[vb + (((wv * 2 + 0) ^ (lane & 7)) << 3)] = vh0.v;
        *(bf16x8*)&Vh[vb + (((wv * 2 + 1) ^ (lane & 7)) << 3)] = vh1.v;
        *(bf16x8*)&Vl[vb + (((wv * 2 + 0) ^ (lane & 7)) << 3)] = vl0.v;
        *(bf16x8*)&Vl[vb + (((wv * 2 + 1) ^ (lane & 7)) << 3)] = vl1.v;
    };

    f32x4 acc_o[4];
    #pragma unroll
    for (int i = 0; i < 4; ++i) { f32x4 z = {0,0,0,0}; acc_o[i] = z; }
    float m_run = -INFINITY, l_run = 0.0f;

    u16* Phw = Ph + wv * 1024;
    u16* Plw = Pl + wv * 1024;

    load_tile(0);
    write_tile();
    __syncthreads();

    for (int kt = 0; kt < 16; ++kt) {
        if (kt < 15) load_tile(kt + 1);  // issue next-tile globals under compute

        // --- S^T = mfma(K, Q), split 3-product ---
        f32x4 accs[4];
        #pragma unroll
        for (int i = 0; i < 4; ++i) { f32x4 z = {0,0,0,0}; accs[i] = z; }
        #pragma unroll
        for (int ds = 0; ds < 2; ++ds) {
            #pragma unroll
            for (int sub = 0; sub < 4; ++sub) {
                const int row = sub * 16 + m16;
                const int idx = row * 64 + (((ds * 4 + g8) ^ (m16 & 7)) << 3);
                bf16x8 kh = *(const bf16x8*)&Kh[idx];
                bf16x8 kl = *(const bf16x8*)&Kl[idx];
                accs[sub] = __builtin_amdgcn_mfma_f32_16x16x32_bf16(kh, qh[ds], accs[sub], 0, 0, 0);
                accs[sub] = __builtin_amdgcn_mfma_f32_16x16x32_bf16(kl, qh[ds], accs[sub], 0, 0, 0);
                accs[sub] = __builtin_amdgcn_mfma_f32_16x16x32_bf16(kh, ql[ds], accs[sub], 0, 0, 0);
            }
        }

        // --- online softmax (lane-local row q = m16; reduce across g8 groups) ---
        float mt = accs[0][0];
        #pragma unroll
        for (int sub = 0; sub < 4; ++sub)
            #pragma unroll
            for (int e = 0; e < 4; ++e) mt = fmaxf(mt, accs[sub][e]);
        mt = fmaxf(mt, __shfl_xor(mt, 16));
        mt = fmaxf(mt, __shfl_xor(mt, 32));
        const float mnew = fmaxf(m_run, mt);
        const float fsc = __expf(m_run - mnew);
        float p[4][4];
        float ts = 0.0f;
        #pragma unroll
        for (int sub = 0; sub < 4; ++sub)
            #pragma unroll
            for (int e = 0; e < 4; ++e) {
                p[sub][e] = __expf(accs[sub][e] - mnew);
                ts += p[sub][e];
            }
        ts += __shfl_xor(ts, 16);
        ts += __shfl_xor(ts, 32);
        l_run = l_run * fsc + ts;
        m_run = mnew;
        #pragma unroll
        for (int d = 0; d < 4; ++d)
            #pragma unroll
            for (int e = 0; e < 4; ++e) acc_o[d][e] *= fsc;

        // --- P split -> per-wave LDS slice (wave-local, no barrier) ---
        #pragma unroll
        for (int sub = 0; sub < 4; ++sub)
            #pragma unroll
            for (int pp = 0; pp < 2; ++pp) {
                float p0 = p[sub][2 * pp], p1 = p[sub][2 * pp + 1];
                u16 h0, l0, h1, l1;
                split_bf16(p0, h0, l0);
                split_bf16(p1, h1, l1);
                unsigned hw = (unsigned)h0 | ((unsigned)h1 << 16);
                unsigned lw = (unsigned)l0 | ((unsigned)l1 << 16);
                const int idx = m16 * 64 + (((2 * sub + (g8 >> 1)) ^ (m16 & 7)) << 3)
                                + 4 * (g8 & 1) + 2 * pp;
                *(unsigned*)&Phw[idx] = hw;
                *(unsigned*)&Plw[idx] = lw;
            }

        // --- re-read P as B-fragments ---
        bf16x8 pfh[2], pfl[2];
        #pragma unroll
        for (int ks = 0; ks < 2; ++ks) {
            const int idx = m16 * 64 + (((ks * 4 + g8) ^ (m16 & 7)) << 3);
            pfh[ks] = *(const bf16x8*)&Phw[idx];
            pfl[ks] = *(const bf16x8*)&Plw[idx];
        }

        // --- O^T += mfma(Vt, P), split 3-product ---
        #pragma unroll
        for (int dsub = 0; dsub < 4; ++dsub) {
            #pragma unroll
            for (int ks = 0; ks < 2; ++ks) {
                const int vrow = dsub * 16 + m16;
                const int vidx = vrow * 64 + (((ks * 4 + g8) ^ (m16 & 7)) << 3);
                bf16x8 vh = *(const bf16x8*)&Vh[vidx];
                bf16x8 vl = *(const bf16x8*)&Vl[vidx];
                acc_o[dsub] = __builtin_amdgcn_mfma_f32_16x16x32_bf16(vh, pfh[ks], acc_o[dsub], 0, 0, 0);
                acc_o[dsub] = __builtin_amdgcn_mfma_f32_16x16x32_bf16(vh, pfl[ks], acc_o[dsub], 0, 0, 0);
                acc_o[dsub] = __builtin_amdgcn_mfma_f32_16x16x32_bf16(vl, pfh[ks], acc_o[dsub], 0, 0, 0);
            }
        }

        __syncthreads();                       // all waves done reading K/Vt
        if (kt < 15) { write_tile(); __syncthreads(); }
    }

    // --- epilogue: normalize, split, transpose through P region, store ---
    const float linv = 1.0f / l_run;
    #pragma unroll
    for (int dsub = 0; dsub < 4; ++dsub)
        #pragma unroll
        for (int pp = 0; pp < 2; ++pp) {
            float o0 = acc_o[dsub][2 * pp] * linv;
            float o1 = acc_o[dsub][2 * pp + 1] * linv;
            u16 h0, l0, h1, l1;
            split_bf16(o0, h0, l0);
            split_bf16(o1, h1, l1);
            unsigned hw = (unsigned)h0 | ((unsigned)h1 << 16);
            unsigned lw = (unsigned)l0 | ((unsigned)l1 << 16);
            const int idx = m16 * 64 + (((2 * dsub + (g8 >> 1)) ^ (m16 & 7)) << 3)
                            + 4 * (g8 & 1) + 2 * pp;
            *(unsigned*)&Phw[idx] = hw;    // O rows live in this wave's q-slice
            *(unsigned*)&Plw[idx] = lw;
        }
    __syncthreads();
    #pragma unroll
    for (int i = 0; i < 2; ++i) {
        int s = t + 256 * i;
        int q_l = s >> 3, dg8 = s & 7;
        const int idx = q_l * 64 + ((dg8 ^ (q_l & 7)) << 3);
        bf16x8 oh = *(const bf16x8*)&Ph[idx];
        bf16x8 ol = *(const bf16x8*)&Pl[idx];
        size_t off = (size_t)(b * T_SEQ + q0 + q_l) * C_DIM + h * HD + dg8 * 8;
        *(bf16x8*)&att_hi[off] = oh;
        *(bf16x8*)&att_lo[off] = ol;
    }
}

// ---------------------------------------------------------------------------
extern "C" void kernel_launch(void* const* d_in, const int* in_sizes, int n_in,
                              void* d_out, int out_size, void* d_ws, size_t ws_size,
                              hipStream_t stream) {
    const float* x      = (const float*)d_in[0];
    const float* norm_g = (const float*)d_in[1];
    const float* norm_b = (const float*)d_in[2];
    const float* qkv_w  = (const float*)d_in[3];
    const float* qkv_b  = (const float*)d_in[4];
    const float* qln_g  = (const float*)d_in[5];
    const float* qln_b  = (const float*)d_in[6];
    const float* kln_g  = (const float*)d_in[7];
    const float* kln_b  = (const float*)d_in[8];
    const float* proj_w = (const float*)d_in[9];
    const float* proj_b = (const float*)d_in[10];
    float* out = (float*)d_out;

    char* w = (char*)d_ws;
    float* qkv  = (float*)w;                          // 4096*3072*4 = 50331648
    u16* xn_hi  = (u16*)(w + 50331648);               // 4096*1024*2 =  8388608
    u16* xn_lo  = (u16*)(w + 58720256);
    u16* wq_hi  = (u16*)(w + 67108864);               // 3072*1024*2
    u16* wq_lo  = (u16*)(w + 73400320);
    u16* pw_hi  = (u16*)(w + 79691776);               // 1024*1024*2
    u16* pw_lo  = (u16*)(w + 81788928);
    u16* att_hi = xn_hi;   // xn dead after qkv GEMM
    u16* att_lo = xn_lo;

    const int rows = NB * T_SEQ;  // 4096

    ln_split_kernel<<<rows, 256, 0, stream>>>(x, xn_hi, xn_lo, norm_g, norm_b);
    wsplit_t<<<dim3(C3 / 64, C_DIM / 64), 256, 0, stream>>>(qkv_w, wq_hi, wq_lo, C_DIM, C3);
    wsplit_t<<<dim3(C_DIM / 64, C_DIM / 64), 256, 0, stream>>>(proj_w, pw_hi, pw_lo, C_DIM, C_DIM);
    gemm_mfma_split<<<dim3(C3 / 128, rows / 128), 256, 0, stream>>>(
        xn_hi, xn_lo, wq_hi, wq_lo, qkv_b, qkv, rows, C3, C_DIM);
    ln_qk_kernel<<<2 * rows, 256, 0, stream>>>(qkv, qln_g, qln_b, kln_g, kln_b);
    attn_mfma<<<NB * NH * (T_SEQ / 64), 256, 0, stream>>>(qkv, att_hi, att_lo);
    gemm_mfma_split<<<dim3(C_DIM / 128, rows / 128), 256, 0, stream>>>(
        att_hi, att_lo, pw_hi, pw_lo, proj_b, out, rows, C_DIM, C_DIM);
}

// Round 5
// 337.285 us; speedup vs baseline: 2.5563x; 1.0154x over previous
//
#include <hip/hip_runtime.h>
#include <math.h>

#define T_SEQ 1024
#define C_DIM 1024
#define NB    4
#define NH    16
#define HD    64
#define C3    3072

typedef __attribute__((ext_vector_type(8))) short bf16x8;
typedef __attribute__((ext_vector_type(4))) float f32x4;
typedef unsigned short u16;

union B8 { bf16x8 v; u16 u[8]; unsigned d[4]; };

__device__ inline u16 bf16_rtn(float v) {
    unsigned int u = __float_as_uint(v);
    u += 0x7FFFu + ((u >> 16) & 1u);
    return (u16)(u >> 16);
}
__device__ inline void split_bf16(float v, u16& hi, u16& lo) {
    hi = bf16_rtn(v);
    float hif = __uint_as_float(((unsigned int)hi) << 16);
    lo = bf16_rtn(v - hif);
}

// ---------------------------------------------------------------------------
// LayerNorm fp32 -> split bf16 hi/lo (row stride 1024 both sides).
// ---------------------------------------------------------------------------
__global__ __launch_bounds__(256) void ln_split_kernel(const float* __restrict__ in,
                                                       u16* __restrict__ oh,
                                                       u16* __restrict__ ol,
                                                       const float* __restrict__ g,
                                                       const float* __restrict__ beta) {
    const int row = blockIdx.x;
    const float* x = in + (size_t)row * 1024;
    const int t = threadIdx.x;

    float4 v = *(const float4*)&x[t * 4];
    float s  = v.x + v.y + v.z + v.w;
    float ss = v.x * v.x + v.y * v.y + v.z * v.z + v.w * v.w;
    #pragma unroll
    for (int m = 1; m < 64; m <<= 1) {
        s  += __shfl_xor(s, m);
        ss += __shfl_xor(ss, m);
    }
    __shared__ float red[8];
    const int wave = t >> 6, lane = t & 63;
    if (lane == 0) { red[wave * 2] = s; red[wave * 2 + 1] = ss; }
    __syncthreads();
    s  = red[0] + red[2] + red[4] + red[6];
    ss = red[1] + red[3] + red[5] + red[7];

    const float mu   = s * (1.0f / 1024.0f);
    const float var  = ss * (1.0f / 1024.0f) - mu * mu;
    const float rstd = rsqrtf(var + 1e-5f);

    float4 gg = *(const float4*)&g[t * 4];
    float4 bb = *(const float4*)&beta[t * 4];
    float o[4];
    o[0] = (v.x - mu) * rstd * gg.x + bb.x;
    o[1] = (v.y - mu) * rstd * gg.y + bb.y;
    o[2] = (v.z - mu) * rstd * gg.z + bb.z;
    o[3] = (v.w - mu) * rstd * gg.w + bb.w;

    ushort4 h4, l4;
    split_bf16(o[0], h4.x, l4.x);
    split_bf16(o[1], h4.y, l4.y);
    split_bf16(o[2], h4.z, l4.z);
    split_bf16(o[3], h4.w, l4.w);
    size_t off = (size_t)row * 1024 + t * 4;
    *(ushort4*)&oh[off] = h4;
    *(ushort4*)&ol[off] = l4;
}

// ---------------------------------------------------------------------------
// Fused Q/K LayerNorm. Q: in-place fp32 (stride 3072). K: no fp32 writeback —
// writes split bf16 in head-gathered layout Kh/Kl[(b*16+h)*1024 + t][64].
// ---------------------------------------------------------------------------
__global__ __launch_bounds__(256) void ln_qk_kernel(float* __restrict__ qkv,
                                                    const float* __restrict__ qg,
                                                    const float* __restrict__ qb,
                                                    const float* __restrict__ kg,
                                                    const float* __restrict__ kb,
                                                    u16* __restrict__ Kh,
                                                    u16* __restrict__ Kl) {
    const int row = blockIdx.x;
    const int isK = row >> 12;
    const int r = row & 4095;
    float* x = qkv + (size_t)r * C3 + (isK ? 1024 : 0);
    const float* g    = isK ? kg : qg;
    const float* beta = isK ? kb : qb;
    const int t = threadIdx.x;

    float4 v = *(const float4*)&x[t * 4];
    float s  = v.x + v.y + v.z + v.w;
    float ss = v.x * v.x + v.y * v.y + v.z * v.z + v.w * v.w;
    #pragma unroll
    for (int m = 1; m < 64; m <<= 1) {
        s  += __shfl_xor(s, m);
        ss += __shfl_xor(ss, m);
    }
    __shared__ float red[8];
    const int wave = t >> 6, lane = t & 63;
    if (lane == 0) { red[wave * 2] = s; red[wave * 2 + 1] = ss; }
    __syncthreads();
    s  = red[0] + red[2] + red[4] + red[6];
    ss = red[1] + red[3] + red[5] + red[7];

    const float mu   = s * (1.0f / 1024.0f);
    const float var  = ss * (1.0f / 1024.0f) - mu * mu;
    const float rstd = rsqrtf(var + 1e-5f);

    float4 gg = *(const float4*)&g[t * 4];
    float4 bb = *(const float4*)&beta[t * 4];
    float o0 = (v.x - mu) * rstd * gg.x + bb.x;
    float o1 = (v.y - mu) * rstd * gg.y + bb.y;
    float o2 = (v.z - mu) * rstd * gg.z + bb.z;
    float o3 = (v.w - mu) * rstd * gg.w + bb.w;

    if (!isK) {
        float4 o = {o0, o1, o2, o3};
        *(float4*)&x[t * 4] = o;
    } else {
        ushort4 h4, l4;
        split_bf16(o0, h4.x, l4.x);
        split_bf16(o1, h4.y, l4.y);
        split_bf16(o2, h4.z, l4.z);
        split_bf16(o3, h4.w, l4.w);
        const int c = t * 4;
        const int hh = c >> 6, d = c & 63;
        const int b = r >> 10, tt = r & 1023;
        size_t off = ((size_t)((b << 4) + hh) << 16) + (size_t)tt * 64 + d;
        *(ushort4*)&Kh[off] = h4;
        *(ushort4*)&Kl[off] = l4;
    }
}

// ---------------------------------------------------------------------------
// V split + per-head transpose: qkv V region fp32 [t][d] -> Vth/Vtl
// [(b*16+h)*64 + d][1024 t] bf16. One block per (b,h,ttile of 64).
// ---------------------------------------------------------------------------
__global__ __launch_bounds__(256) void vsplit_t(const float* __restrict__ qkv,
                                                u16* __restrict__ Vth,
                                                u16* __restrict__ Vtl) {
    __shared__ float tile[64][68];
    const int bid = blockIdx.x;
    const int tt = bid & 15, h = (bid >> 4) & 15, b = bid >> 8;
    const int t = threadIdx.x;
    const float* src = qkv + (size_t)(b * 1024 + tt * 64) * C3 + 2048 + h * 64;
    #pragma unroll
    for (int i = 0; i < 4; ++i) {
        int idx = i * 256 + t;
        int tr = idx >> 4, dc = (idx & 15) * 4;
        float4 v = *(const float4*)&src[(size_t)tr * C3 + dc];
        tile[tr][dc + 0] = v.x; tile[tr][dc + 1] = v.y;
        tile[tr][dc + 2] = v.z; tile[tr][dc + 3] = v.w;
    }
    __syncthreads();
    #pragma unroll
    for (int i = 0; i < 4; ++i) {
        int idx = i * 256 + t;
        int d = idx >> 4, tc = (idx & 15) * 4;
        ushort4 h4, l4;
        split_bf16(tile[tc + 0][d], h4.x, l4.x);
        split_bf16(tile[tc + 1][d], h4.y, l4.y);
        split_bf16(tile[tc + 2][d], h4.z, l4.z);
        split_bf16(tile[tc + 3][d], h4.w, l4.w);
        size_t off = ((size_t)((b * 16 + h) * 64 + d)) * 1024 + tt * 64 + tc;
        *(ushort4*)&Vth[off] = h4;
        *(ushort4*)&Vtl[off] = l4;
    }
}

// ---------------------------------------------------------------------------
// Weight split + transpose: W[K][N] fp32 -> Th/Tl[N][K] bf16, out row stride
// ldt (u16 units) so outputs can overlay strided regions.
// ---------------------------------------------------------------------------
__global__ __launch_bounds__(256) void wsplit_t(const float* __restrict__ W,
                                                u16* __restrict__ Th,
                                                u16* __restrict__ Tl,
                                                int K, int N, int ldt) {
    __shared__ float tile[64][69];
    const int n0 = blockIdx.x * 64, k0 = blockIdx.y * 64;
    const int t = threadIdx.x;
    #pragma unroll
    for (int i = 0; i < 4; ++i) {
        int idx = t + 256 * i;
        int kr = idx >> 4, nc = (idx & 15) * 4;
        float4 v = *(const float4*)&W[(size_t)(k0 + kr) * N + n0 + nc];
        tile[kr][nc + 0] = v.x; tile[kr][nc + 1] = v.y;
        tile[kr][nc + 2] = v.z; tile[kr][nc + 3] = v.w;
    }
    __syncthreads();
    #pragma unroll
    for (int i = 0; i < 4; ++i) {
        int idx = t + 256 * i;
        int nr = idx >> 4, kc = (idx & 15) * 4;
        ushort4 h4, l4;
        split_bf16(tile[kc + 0][nr], h4.x, l4.x);
        split_bf16(tile[kc + 1][nr], h4.y, l4.y);
        split_bf16(tile[kc + 2][nr], h4.z, l4.z);
        split_bf16(tile[kc + 3][nr], h4.w, l4.w);
        size_t o = (size_t)(n0 + nr) * ldt + k0 + kc;
        *(ushort4*)&Th[o] = h4;
        *(ushort4*)&Tl[o] = l4;
    }
}

// ---------------------------------------------------------------------------
// Split-bf16 MFMA GEMM: C = (Ah+Al) @ (Bh+Bl)^T + bias. A row stride lda,
// B row stride ldb (u16 units) — supports strided overlays.
// ---------------------------------------------------------------------------
__global__ __launch_bounds__(256) void gemm_mfma_split(
    const u16* __restrict__ Ah, const u16* __restrict__ Al,
    const u16* __restrict__ Bh, const u16* __restrict__ Bl,
    const float* __restrict__ bias, float* __restrict__ C,
    int M, int N, int K, int lda, int ldb) {
    __shared__ u16 sAh[128 * 32], sAl[128 * 32], sBh[128 * 32], sBl[128 * 32];

    const int t    = threadIdx.x;
    const int lane = t & 63;
    const int wid  = t >> 6;
    const int wr   = wid >> 1, wc = wid & 1;

    const int nbx = gridDim.x;
    const int nwg = nbx * gridDim.y;
    int bid = blockIdx.y * nbx + blockIdx.x;
    int swz = (bid & 7) * (nwg >> 3) + (bid >> 3);
    const int bn = (swz % nbx) * 128;
    const int bm = (swz / nbx) * 128;

    const int jr    = lane >> 2;
    const int cphys = lane & 3;
    const int m16 = lane & 15, g8 = lane >> 4;

    f32x4 acc[4][4];
    #pragma unroll
    for (int m = 0; m < 4; ++m)
        #pragma unroll
        for (int n = 0; n < 4; ++n) {
            f32x4 z = {0.0f, 0.0f, 0.0f, 0.0f};
            acc[m][n] = z;
        }

    for (int k0 = 0; k0 < K; k0 += 32) {
        __syncthreads();
        #pragma unroll
        for (int jj = 0; jj < 2; ++jj) {
            const int j = wid * 2 + jj;
            const int r = (j << 4) + jr;
            const int cl = cphys ^ (r & 3);
            const size_t ga = ((size_t)(bm + r) * lda + k0 + (cl << 3)) * 2;
            const size_t gb = ((size_t)(bn + r) * ldb + k0 + (cl << 3)) * 2;
            const unsigned ldso = (unsigned)(j << 10);
            __builtin_amdgcn_global_load_lds(
                (const __attribute__((address_space(1))) void*)((const char*)Ah + ga),
                (__attribute__((address_space(3))) void*)((char*)sAh + ldso), 16, 0, 0);
            __builtin_amdgcn_global_load_lds(
                (const __attribute__((address_space(1))) void*)((const char*)Al + ga),
                (__attribute__((address_space(3))) void*)((char*)sAl + ldso), 16, 0, 0);
            __builtin_amdgcn_global_load_lds(
                (const __attribute__((address_space(1))) void*)((const char*)Bh + gb),
                (__attribute__((address_space(3))) void*)((char*)sBh + ldso), 16, 0, 0);
            __builtin_amdgcn_global_load_lds(
                (const __attribute__((address_space(1))) void*)((const char*)Bl + gb),
                (__attribute__((address_space(3))) void*)((char*)sBl + ldso), 16, 0, 0);
        }
        __syncthreads();

        bf16x8 ah[4], al[4], bh[4], bl[4];
        #pragma unroll
        for (int m = 0; m < 4; ++m) {
            const int r = wr * 64 + m * 16 + m16;
            const int off = (r << 5) + ((g8 ^ (m16 & 3)) << 3);
            ah[m] = *(const bf16x8*)&sAh[off];
            al[m] = *(const bf16x8*)&sAl[off];
        }
        #pragma unroll
        for (int n = 0; n < 4; ++n) {
            const int r = wc * 64 + n * 16 + m16;
            const int off = (r << 5) + ((g8 ^ (m16 & 3)) << 3);
            bh[n] = *(const bf16x8*)&sBh[off];
            bl[n] = *(const bf16x8*)&sBl[off];
        }
        #pragma unroll
        for (int m = 0; m < 4; ++m)
            #pragma unroll
            for (int n = 0; n < 4; ++n) {
                acc[m][n] = __builtin_amdgcn_mfma_f32_16x16x32_bf16(ah[m], bh[n], acc[m][n], 0, 0, 0);
                acc[m][n] = __builtin_amdgcn_mfma_f32_16x16x32_bf16(al[m], bh[n], acc[m][n], 0, 0, 0);
                acc[m][n] = __builtin_amdgcn_mfma_f32_16x16x32_bf16(ah[m], bl[n], acc[m][n], 0, 0, 0);
            }
    }

    #pragma unroll
    for (int m = 0; m < 4; ++m) {
        const int row0 = bm + wr * 64 + m * 16 + (g8 << 2);
        #pragma unroll
        for (int n = 0; n < 4; ++n) {
            const int col = bn + wc * 64 + n * 16 + m16;
            const float bv = bias[col];
            #pragma unroll
            for (int e = 0; e < 4; ++e)
                C[(size_t)(row0 + e) * N + col] = acc[m][n][e] + bv;
        }
    }
}

// ---------------------------------------------------------------------------
// MFMA flash attention. K/Vt pre-split bf16 staged via global_load_lds.
// Single K buffer + double-buffered Vt; stage(kt+1) issued after post-QK^T
// barrier so loads hide under softmax+PV. Raw s_barrier + vmcnt(0).
// LDS 64 KB: K 16 | V0 16 | V1 16 | P 16.
// Output written as split bf16 into the (dead) K region of qkv (u16 overlay).
// ---------------------------------------------------------------------------
__global__ __launch_bounds__(256) void attn_mfma(const float* __restrict__ qkv,
                                                 const u16* __restrict__ Kh,
                                                 const u16* __restrict__ Kl,
                                                 const u16* __restrict__ Vth,
                                                 const u16* __restrict__ Vtl,
                                                 u16* __restrict__ att) {
    __shared__ __align__(16) u16 SM[32768];  // 64 KB
    // u16 offsets: Kh 0 | Kl 4096 | V0h 8192 | V0l 12288 | V1h 16384 |
    //              V1l 20480 | Ph 24576 | Pl 28672

    const int t    = threadIdx.x;
    const int lane = t & 63;
    const int wv   = t >> 6;
    const int m16  = lane & 15, g8 = lane >> 4;

    const int bid  = blockIdx.x;
    const int work = (bid & 7) * 128 + (bid >> 3);
    const int qt = work & 15;
    const int bh = work >> 4;
    const int h  = bh & 15;
    const int b  = bh >> 4;
    const int q0 = qt * 64;

    // staging geometry (per lane)
    const int srow = lane >> 3;            // row within a wave's 8-row group
    const int scl  = (lane & 7) ^ srow;    // logical chunk for this phys slot
    const size_t kvrow0 = (size_t)bh << 16;  // bh*65536

    auto stageK = [&](int kt) {
        const int kb = kt * 64;
        #pragma unroll
        for (int issue = 0; issue < 2; ++issue) {
            const int rloc = (issue * 4 + wv) * 8 + srow;
            const size_t go = (kvrow0 + (size_t)(kb + rloc) * 64 + scl * 8) * 2;
            const unsigned lo = (unsigned)((issue * 4 + wv) * 1024);
            __builtin_amdgcn_global_load_lds(
                (const __attribute__((address_space(1))) void*)((const char*)Kh + go),
                (__attribute__((address_space(3))) void*)((char*)SM + lo), 16, 0, 0);
            __builtin_amdgcn_global_load_lds(
                (const __attribute__((address_space(1))) void*)((const char*)Kl + go),
                (__attribute__((address_space(3))) void*)((char*)SM + 8192 + lo), 16, 0, 0);
        }
    };
    auto stageV = [&](int kt, int bsel) {
        const int kb = kt * 64;
        #pragma unroll
        for (int issue = 0; issue < 2; ++issue) {
            const int rloc = (issue * 4 + wv) * 8 + srow;   // d row
            const size_t go = (kvrow0 + (size_t)rloc * 1024 + kb + scl * 8) * 2;
            const unsigned lo = (unsigned)(16384 + bsel * 16384 + (issue * 4 + wv) * 1024);
            __builtin_amdgcn_global_load_lds(
                (const __attribute__((address_space(1))) void*)((const char*)Vth + go),
                (__attribute__((address_space(3))) void*)((char*)SM + lo), 16, 0, 0);
            __builtin_amdgcn_global_load_lds(
                (const __attribute__((address_space(1))) void*)((const char*)Vtl + go),
                (__attribute__((address_space(3))) void*)((char*)SM + 8192 + lo), 16, 0, 0);
        }
    };

    // --- Q fragments in registers (scaled by 1/sqrt(D), split hi/lo) ---
    bf16x8 qh[2], ql[2];
    {
        const float* qrow = qkv + (size_t)(b * T_SEQ + q0 + wv * 16 + m16) * C3 + h * HD;
        #pragma unroll
        for (int ds = 0; ds < 2; ++ds) {
            float4 a = *(const float4*)&qrow[ds * 32 + g8 * 8];
            float4 c = *(const float4*)&qrow[ds * 32 + g8 * 8 + 4];
            float q8[8] = {a.x, a.y, a.z, a.w, c.x, c.y, c.z, c.w};
            B8 hh, ll;
            #pragma unroll
            for (int j = 0; j < 8; ++j) {
                u16 hi, lo;
                split_bf16(q8[j] * 0.125f, hi, lo);
                hh.u[j] = hi; ll.u[j] = lo;
            }
            qh[ds] = hh.v; ql[ds] = ll.v;
        }
    }

    f32x4 acc_o[4];
    #pragma unroll
    for (int i = 0; i < 4; ++i) { f32x4 z = {0, 0, 0, 0}; acc_o[i] = z; }
    float m_run = -INFINITY, l_run = 0.0f;

    u16* Phw = SM + 24576 + wv * 1024;
    u16* Plw = SM + 28672 + wv * 1024;

    stageK(0);
    stageV(0, 0);
    asm volatile("s_waitcnt vmcnt(0)" ::: "memory");
    __builtin_amdgcn_s_barrier();
    __builtin_amdgcn_sched_barrier(0);

    int vsel = 0;
    for (int kt = 0; kt < 16; ++kt) {
        // --- S^T = mfma(K, Q), split 3-product ---
        f32x4 accs[4];
        #pragma unroll
        for (int i = 0; i < 4; ++i) { f32x4 z = {0, 0, 0, 0}; accs[i] = z; }
        #pragma unroll
        for (int ds = 0; ds < 2; ++ds) {
            #pragma unroll
            for (int sub = 0; sub < 4; ++sub) {
                const int row = sub * 16 + m16;
                const int idx = row * 64 + ((((ds * 4 + g8)) ^ (m16 & 7)) << 3);
                bf16x8 kh = *(const bf16x8*)&SM[idx];
                bf16x8 kl = *(const bf16x8*)&SM[4096 + idx];
                accs[sub] = __builtin_amdgcn_mfma_f32_16x16x32_bf16(kh, qh[ds], accs[sub], 0, 0, 0);
                accs[sub] = __builtin_amdgcn_mfma_f32_16x16x32_bf16(kl, qh[ds], accs[sub], 0, 0, 0);
                accs[sub] = __builtin_amdgcn_mfma_f32_16x16x32_bf16(kh, ql[ds], accs[sub], 0, 0, 0);
            }
        }

        // barrier A: everyone done reading Kbuf -> safe to overwrite
        __builtin_amdgcn_sched_barrier(0);
        __builtin_amdgcn_s_barrier();
        __builtin_amdgcn_sched_barrier(0);
        if (kt < 15) { stageK(kt + 1); stageV(kt + 1, vsel ^ 1); }

        // --- online softmax (row q = m16 lane-local; reduce across g8) ---
        float mt = accs[0][0];
        #pragma unroll
        for (int sub = 0; sub < 4; ++sub)
            #pragma unroll
            for (int e = 0; e < 4; ++e) mt = fmaxf(mt, accs[sub][e]);
        mt = fmaxf(mt, __shfl_xor(mt, 16));
        mt = fmaxf(mt, __shfl_xor(mt, 32));
        const float mnew = fmaxf(m_run, mt);
        const float fsc = __expf(m_run - mnew);
        float p[4][4];
        float ts = 0.0f;
        #pragma unroll
        for (int sub = 0; sub < 4; ++sub)
            #pragma unroll
            for (int e = 0; e < 4; ++e) {
                p[sub][e] = __expf(accs[sub][e] - mnew);
                ts += p[sub][e];
            }
        ts += __shfl_xor(ts, 16);
        ts += __shfl_xor(ts, 32);
        l_run = l_run * fsc + ts;
        m_run = mnew;
        #pragma unroll
        for (int d = 0; d < 4; ++d)
            #pragma unroll
            for (int e = 0; e < 4; ++e) acc_o[d][e] *= fsc;

        // --- P split -> per-wave LDS slice (wave-local) ---
        #pragma unroll
        for (int sub = 0; sub < 4; ++sub)
            #pragma unroll
            for (int pp = 0; pp < 2; ++pp) {
                float p0 = p[sub][2 * pp], p1 = p[sub][2 * pp + 1];
                u16 h0, l0, h1, l1;
                split_bf16(p0, h0, l0);
                split_bf16(p1, h1, l1);
                unsigned hw = (unsigned)h0 | ((unsigned)h1 << 16);
                unsigned lw = (unsigned)l0 | ((unsigned)l1 << 16);
                const int idx = m16 * 64 + (((2 * sub + (g8 >> 1)) ^ (m16 & 7)) << 3)
                                + 4 * (g8 & 1) + 2 * pp;
                *(unsigned*)&Phw[idx] = hw;
                *(unsigned*)&Plw[idx] = lw;
            }

        bf16x8 pfh[2], pfl[2];
        #pragma unroll
        for (int ks = 0; ks < 2; ++ks) {
            const int idx = m16 * 64 + ((((ks * 4 + g8)) ^ (m16 & 7)) << 3);
            pfh[ks] = *(const bf16x8*)&Phw[idx];
            pfl[ks] = *(const bf16x8*)&Plw[idx];
        }

        // --- O^T += mfma(Vt, P), split 3-product, from Vbuf[vsel] ---
        const int vb = 8192 + vsel * 8192;
        #pragma unroll
        for (int dsub = 0; dsub < 4; ++dsub) {
            #pragma unroll
            for (int ks = 0; ks < 2; ++ks) {
                const int vrow = dsub * 16 + m16;
                const int vidx = vb + vrow * 64 + ((((ks * 4 + g8)) ^ (m16 & 7)) << 3);
                bf16x8 vh = *(const bf16x8*)&SM[vidx];
                bf16x8 vl = *(const bf16x8*)&SM[4096 + vidx];
                acc_o[dsub] = __builtin_amdgcn_mfma_f32_16x16x32_bf16(vh, pfh[ks], acc_o[dsub], 0, 0, 0);
                acc_o[dsub] = __builtin_amdgcn_mfma_f32_16x16x32_bf16(vh, pfl[ks], acc_o[dsub], 0, 0, 0);
                acc_o[dsub] = __builtin_amdgcn_mfma_f32_16x16x32_bf16(vl, pfh[ks], acc_o[dsub], 0, 0, 0);
            }
        }

        // barrier B: wait staged loads (mostly hidden), everyone past Vbuf[vsel]
        __builtin_amdgcn_sched_barrier(0);
        asm volatile("s_waitcnt vmcnt(0)" ::: "memory");
        __builtin_amdgcn_s_barrier();
        __builtin_amdgcn_sched_barrier(0);
        vsel ^= 1;
    }

    // --- epilogue: normalize, split, transpose through P region, store ---
    const float linv = 1.0f / l_run;
    #pragma unroll
    for (int dsub = 0; dsub < 4; ++dsub)
        #pragma unroll
        for (int pp = 0; pp < 2; ++pp) {
            float o0 = acc_o[dsub][2 * pp] * linv;
            float o1 = acc_o[dsub][2 * pp + 1] * linv;
            u16 h0, l0, h1, l1;
            split_bf16(o0, h0, l0);
            split_bf16(o1, h1, l1);
            unsigned hw = (unsigned)h0 | ((unsigned)h1 << 16);
            unsigned lw = (unsigned)l0 | ((unsigned)l1 << 16);
            const int idx = m16 * 64 + (((2 * dsub + (g8 >> 1)) ^ (m16 & 7)) << 3)
                            + 4 * (g8 & 1) + 2 * pp;
            *(unsigned*)&Phw[idx] = hw;
            *(unsigned*)&Plw[idx] = lw;
        }
    __syncthreads();
    #pragma unroll
    for (int i = 0; i < 2; ++i) {
        int s = t + 256 * i;
        int q_l = s >> 3, dg8 = s & 7;
        const int idx = q_l * 64 + ((dg8 ^ (q_l & 7)) << 3);
        bf16x8 oh = *(const bf16x8*)&SM[24576 + idx];
        bf16x8 ol = *(const bf16x8*)&SM[28672 + idx];
        // overlay into dead K region of qkv: row stride 6144 u16
        size_t off = (size_t)(b * T_SEQ + q0 + q_l) * 6144 + 2048 + h * HD + dg8 * 8;
        *(bf16x8*)&att[off] = oh;
        *(bf16x8*)&att[off + 1024] = ol;
    }
}

// ---------------------------------------------------------------------------
extern "C" void kernel_launch(void* const* d_in, const int* in_sizes, int n_in,
                              void* d_out, int out_size, void* d_ws, size_t ws_size,
                              hipStream_t stream) {
    const float* x      = (const float*)d_in[0];
    const float* norm_g = (const float*)d_in[1];
    const float* norm_b = (const float*)d_in[2];
    const float* qkv_w  = (const float*)d_in[3];
    const float* qkv_b  = (const float*)d_in[4];
    const float* qln_g  = (const float*)d_in[5];
    const float* qln_b  = (const float*)d_in[6];
    const float* kln_g  = (const float*)d_in[7];
    const float* kln_b  = (const float*)d_in[8];
    const float* proj_w = (const float*)d_in[9];
    const float* proj_b = (const float*)d_in[10];
    float* out = (float*)d_out;

    // workspace layout, 83,886,080 B total (proven budget):
    // [0, 50331648)          qkv fp32 (Q | K->att overlay | V->pw overlay)
    // [50331648, 67108864)   xn_hi/xn_lo  -> reused as Kh/Kl after gemm1
    // [67108864, 83886080)   wq_hi/wq_lo  -> reused as Vth/Vtl after gemm1
    char* w = (char*)d_ws;
    float* qkv    = (float*)w;
    u16* qkv_u16  = (u16*)w;
    u16* xn_hi    = (u16*)(w + 50331648);
    u16* xn_lo    = (u16*)(w + 58720256);
    u16* wq_hi    = (u16*)(w + 67108864);
    u16* wq_lo    = (u16*)(w + 73400320);
    u16* Kh       = xn_hi;
    u16* Kl       = xn_lo;
    u16* Vth      = (u16*)(w + 67108864);
    u16* Vtl      = (u16*)(w + 75497472);
    // proj weights overlay qkv V-region; att overlays qkv K-region
    u16* pw_hi    = qkv_u16 + 4096;  // row n at n*6144 + 4096
    u16* pw_lo    = qkv_u16 + 5120;
    u16* att_hi   = qkv_u16 + 2048;  // row r at r*6144 + 2048
    u16* att_lo   = qkv_u16 + 3072;

    const int rows = NB * T_SEQ;  // 4096

    ln_split_kernel<<<rows, 256, 0, stream>>>(x, xn_hi, xn_lo, norm_g, norm_b);
    wsplit_t<<<dim3(C3 / 64, C_DIM / 64), 256, 0, stream>>>(qkv_w, wq_hi, wq_lo, C_DIM, C3, 1024);
    gemm_mfma_split<<<dim3(C3 / 128, rows / 128), 256, 0, stream>>>(
        xn_hi, xn_lo, wq_hi, wq_lo, qkv_b, qkv, rows, C3, C_DIM, 1024, 1024);
    ln_qk_kernel<<<2 * rows, 256, 0, stream>>>(qkv, qln_g, qln_b, kln_g, kln_b, Kh, Kl);
    vsplit_t<<<1024, 256, 0, stream>>>(qkv, Vth, Vtl);
    wsplit_t<<<dim3(C_DIM / 64, C_DIM / 64), 256, 0, stream>>>(proj_w, pw_hi, pw_lo, C_DIM, C_DIM, 6144);
    attn_mfma<<<1024, 256, 0, stream>>>(qkv, Kh, Kl, Vth, Vtl, qkv_u16);
    gemm_mfma_split<<<dim3(C_DIM / 128, rows / 128), 256, 0, stream>>>(
        att_hi, att_lo, pw_hi, pw_lo, proj_b, out, rows, C_DIM, C_DIM, 6144, 6144);
}

// Round 6
// 330.458 us; speedup vs baseline: 2.6092x; 1.0207x over previous
//
#include <hip/hip_runtime.h>
#include <math.h>

#define T_SEQ 1024
#define C_DIM 1024
#define NB    4
#define NH    16
#define HD    64
#define C3    3072

typedef __attribute__((ext_vector_type(8))) short bf16x8;
typedef __attribute__((ext_vector_type(4))) float f32x4;
typedef unsigned short u16;

union B8 { bf16x8 v; u16 u[8]; unsigned d[4]; };

__device__ inline u16 bf16_rtn(float v) {
    unsigned int u = __float_as_uint(v);
    u += 0x7FFFu + ((u >> 16) & 1u);
    return (u16)(u >> 16);
}
__device__ inline void split_bf16(float v, u16& hi, u16& lo) {
    hi = bf16_rtn(v);
    float hif = __uint_as_float(((unsigned int)hi) << 16);
    lo = bf16_rtn(v - hif);
}

// ---------------------------------------------------------------------------
// LayerNorm fp32 -> split bf16 hi/lo (row stride 1024 both sides).
// ---------------------------------------------------------------------------
__global__ __launch_bounds__(256) void ln_split_kernel(const float* __restrict__ in,
                                                       u16* __restrict__ oh,
                                                       u16* __restrict__ ol,
                                                       const float* __restrict__ g,
                                                       const float* __restrict__ beta) {
    const int row = blockIdx.x;
    const float* x = in + (size_t)row * 1024;
    const int t = threadIdx.x;

    float4 v = *(const float4*)&x[t * 4];
    float s  = v.x + v.y + v.z + v.w;
    float ss = v.x * v.x + v.y * v.y + v.z * v.z + v.w * v.w;
    #pragma unroll
    for (int m = 1; m < 64; m <<= 1) {
        s  += __shfl_xor(s, m);
        ss += __shfl_xor(ss, m);
    }
    __shared__ float red[8];
    const int wave = t >> 6, lane = t & 63;
    if (lane == 0) { red[wave * 2] = s; red[wave * 2 + 1] = ss; }
    __syncthreads();
    s  = red[0] + red[2] + red[4] + red[6];
    ss = red[1] + red[3] + red[5] + red[7];

    const float mu   = s * (1.0f / 1024.0f);
    const float var  = ss * (1.0f / 1024.0f) - mu * mu;
    const float rstd = rsqrtf(var + 1e-5f);

    float4 gg = *(const float4*)&g[t * 4];
    float4 bb = *(const float4*)&beta[t * 4];
    float o[4];
    o[0] = (v.x - mu) * rstd * gg.x + bb.x;
    o[1] = (v.y - mu) * rstd * gg.y + bb.y;
    o[2] = (v.z - mu) * rstd * gg.z + bb.z;
    o[3] = (v.w - mu) * rstd * gg.w + bb.w;

    ushort4 h4, l4;
    split_bf16(o[0], h4.x, l4.x);
    split_bf16(o[1], h4.y, l4.y);
    split_bf16(o[2], h4.z, l4.z);
    split_bf16(o[3], h4.w, l4.w);
    size_t off = (size_t)row * 1024 + t * 4;
    *(ushort4*)&oh[off] = h4;
    *(ushort4*)&ol[off] = l4;
}

// ---------------------------------------------------------------------------
// Fused Q/K LayerNorm. Q: in-place fp32 (stride 3072). K: split bf16 out in
// head-gathered layout Kh/Kl[(b*16+h)*1024 + t][64].
// ---------------------------------------------------------------------------
__global__ __launch_bounds__(256) void ln_qk_kernel(float* __restrict__ qkv,
                                                    const float* __restrict__ qg,
                                                    const float* __restrict__ qb,
                                                    const float* __restrict__ kg,
                                                    const float* __restrict__ kb,
                                                    u16* __restrict__ Kh,
                                                    u16* __restrict__ Kl) {
    const int row = blockIdx.x;
    const int isK = row >> 12;
    const int r = row & 4095;
    float* x = qkv + (size_t)r * C3 + (isK ? 1024 : 0);
    const float* g    = isK ? kg : qg;
    const float* beta = isK ? kb : qb;
    const int t = threadIdx.x;

    float4 v = *(const float4*)&x[t * 4];
    float s  = v.x + v.y + v.z + v.w;
    float ss = v.x * v.x + v.y * v.y + v.z * v.z + v.w * v.w;
    #pragma unroll
    for (int m = 1; m < 64; m <<= 1) {
        s  += __shfl_xor(s, m);
        ss += __shfl_xor(ss, m);
    }
    __shared__ float red[8];
    const int wave = t >> 6, lane = t & 63;
    if (lane == 0) { red[wave * 2] = s; red[wave * 2 + 1] = ss; }
    __syncthreads();
    s  = red[0] + red[2] + red[4] + red[6];
    ss = red[1] + red[3] + red[5] + red[7];

    const float mu   = s * (1.0f / 1024.0f);
    const float var  = ss * (1.0f / 1024.0f) - mu * mu;
    const float rstd = rsqrtf(var + 1e-5f);

    float4 gg = *(const float4*)&g[t * 4];
    float4 bb = *(const float4*)&beta[t * 4];
    float o0 = (v.x - mu) * rstd * gg.x + bb.x;
    float o1 = (v.y - mu) * rstd * gg.y + bb.y;
    float o2 = (v.z - mu) * rstd * gg.z + bb.z;
    float o3 = (v.w - mu) * rstd * gg.w + bb.w;

    if (!isK) {
        float4 o = {o0, o1, o2, o3};
        *(float4*)&x[t * 4] = o;
    } else {
        ushort4 h4, l4;
        split_bf16(o0, h4.x, l4.x);
        split_bf16(o1, h4.y, l4.y);
        split_bf16(o2, h4.z, l4.z);
        split_bf16(o3, h4.w, l4.w);
        const int c = t * 4;
        const int hh = c >> 6, d = c & 63;
        const int b = r >> 10, tt = r & 1023;
        size_t off = ((size_t)((b << 4) + hh) << 16) + (size_t)tt * 64 + d;
        *(ushort4*)&Kh[off] = h4;
        *(ushort4*)&Kl[off] = l4;
    }
}

// ---------------------------------------------------------------------------
// V split + per-head transpose: qkv V region fp32 [t][d] -> Vth/Vtl
// [(b*16+h)*64 + d][1024 t] bf16.
// ---------------------------------------------------------------------------
__global__ __launch_bounds__(256) void vsplit_t(const float* __restrict__ qkv,
                                                u16* __restrict__ Vth,
                                                u16* __restrict__ Vtl) {
    __shared__ float tile[64][68];
    const int bid = blockIdx.x;
    const int tt = bid & 15, h = (bid >> 4) & 15, b = bid >> 8;
    const int t = threadIdx.x;
    const float* src = qkv + (size_t)(b * 1024 + tt * 64) * C3 + 2048 + h * 64;
    #pragma unroll
    for (int i = 0; i < 4; ++i) {
        int idx = i * 256 + t;
        int tr = idx >> 4, dc = (idx & 15) * 4;
        float4 v = *(const float4*)&src[(size_t)tr * C3 + dc];
        tile[tr][dc + 0] = v.x; tile[tr][dc + 1] = v.y;
        tile[tr][dc + 2] = v.z; tile[tr][dc + 3] = v.w;
    }
    __syncthreads();
    #pragma unroll
    for (int i = 0; i < 4; ++i) {
        int idx = i * 256 + t;
        int d = idx >> 4, tc = (idx & 15) * 4;
        ushort4 h4, l4;
        split_bf16(tile[tc + 0][d], h4.x, l4.x);
        split_bf16(tile[tc + 1][d], h4.y, l4.y);
        split_bf16(tile[tc + 2][d], h4.z, l4.z);
        split_bf16(tile[tc + 3][d], h4.w, l4.w);
        size_t off = ((size_t)((b * 16 + h) * 64 + d)) * 1024 + tt * 64 + tc;
        *(ushort4*)&Vth[off] = h4;
        *(ushort4*)&Vtl[off] = l4;
    }
}

// ---------------------------------------------------------------------------
// Weight split + transpose: W[K][N] fp32 -> Th/Tl[N][K] bf16, out row stride
// ldt (u16 units).
// ---------------------------------------------------------------------------
__global__ __launch_bounds__(256) void wsplit_t(const float* __restrict__ W,
                                                u16* __restrict__ Th,
                                                u16* __restrict__ Tl,
                                                int K, int N, int ldt) {
    __shared__ float tile[64][69];
    const int n0 = blockIdx.x * 64, k0 = blockIdx.y * 64;
    const int t = threadIdx.x;
    #pragma unroll
    for (int i = 0; i < 4; ++i) {
        int idx = t + 256 * i;
        int kr = idx >> 4, nc = (idx & 15) * 4;
        float4 v = *(const float4*)&W[(size_t)(k0 + kr) * N + n0 + nc];
        tile[kr][nc + 0] = v.x; tile[kr][nc + 1] = v.y;
        tile[kr][nc + 2] = v.z; tile[kr][nc + 3] = v.w;
    }
    __syncthreads();
    #pragma unroll
    for (int i = 0; i < 4; ++i) {
        int idx = t + 256 * i;
        int nr = idx >> 4, kc = (idx & 15) * 4;
        ushort4 h4, l4;
        split_bf16(tile[kc + 0][nr], h4.x, l4.x);
        split_bf16(tile[kc + 1][nr], h4.y, l4.y);
        split_bf16(tile[kc + 2][nr], h4.z, l4.z);
        split_bf16(tile[kc + 3][nr], h4.w, l4.w);
        size_t o = (size_t)(n0 + nr) * ldt + k0 + kc;
        *(ushort4*)&Th[o] = h4;
        *(ushort4*)&Tl[o] = l4;
    }
}

// ---------------------------------------------------------------------------
// 256x256 counted-vmcnt split GEMM (T3+T4+T5). Plain bf16 with K'=3072:
// region 0: Ah*Bh, region 1: Al*Bh, region 2: Ah*Bl (per-tile base select).
// 8 waves (2Mx4N of 128x64), BK=64, dbuf LDS 128KB, chunk-XOR swizzle.
// Loop: {ds_read, setprio(1), 64 MFMA, setprio(0), barrier, STAGE(t+2),
// vmcnt(8) [never 0], barrier}.
// ---------------------------------------------------------------------------
__global__ __launch_bounds__(512, 2) void gemm256_mfma_split(
    const u16* __restrict__ Ah, const u16* __restrict__ Al,
    const u16* __restrict__ Bh, const u16* __restrict__ Bl,
    const float* __restrict__ bias, float* __restrict__ C,
    int N, int lda, int ldb) {
    __shared__ __align__(16) u16 SM[65536];  // A: [0,32KB)x2bufs, B: [64KB,128KB)

    const int t    = threadIdx.x;
    const int lane = t & 63;
    const int wid  = t >> 6;
    const int wr   = wid >> 2;      // 0..1 -> rows wr*128
    const int wc   = wid & 3;       // 0..3 -> cols wc*64
    const int m16  = lane & 15, g8 = lane >> 4;

    const int nbx = gridDim.x;
    const int nwg = nbx * gridDim.y;
    int bid = blockIdx.y * nbx + blockIdx.x;
    int swz = (bid & 7) * (nwg >> 3) + (bid >> 3);
    const int bn = (swz % nbx) * 256;
    const int bm = (swz / nbx) * 256;

    f32x4 acc[8][4];
    #pragma unroll
    for (int m = 0; m < 8; ++m)
        #pragma unroll
        for (int n = 0; n < 4; ++n) {
            f32x4 z = {0.0f, 0.0f, 0.0f, 0.0f};
            acc[m][n] = z;
        }

    auto STAGE = [&](int tile, int buf) {
        const int reg = tile >> 4;  // 0,1,2
        const u16* Ab = (reg == 1) ? Al : Ah;
        const u16* Bb = (reg == 2) ? Bl : Bh;
        const int kloc = (tile & 15) << 6;
        #pragma unroll
        for (int i = 0; i < 4; ++i) {
            const int idx = i * 512 + t;          // 0..2047
            const int r = idx >> 3;               // 0..255
            const int cl = (idx & 7) ^ (r & 7);   // inverse-swizzled source chunk
            const size_t ga = ((size_t)(bm + r) * lda + kloc + cl * 8) * 2;
            const size_t gb = ((size_t)(bn + r) * ldb + kloc + cl * 8) * 2;
            const unsigned la = (unsigned)(buf * 32768 + idx * 16);
            const unsigned lb = (unsigned)(65536 + buf * 32768 + idx * 16);
            __builtin_amdgcn_global_load_lds(
                (const __attribute__((address_space(1))) void*)((const char*)Ab + ga),
                (__attribute__((address_space(3))) void*)((char*)SM + la), 16, 0, 0);
            __builtin_amdgcn_global_load_lds(
                (const __attribute__((address_space(1))) void*)((const char*)Bb + gb),
                (__attribute__((address_space(3))) void*)((char*)SM + lb), 16, 0, 0);
        }
    };

    STAGE(0, 0);
    STAGE(1, 1);
    asm volatile("s_waitcnt vmcnt(8)" ::: "memory");   // tile 0 landed
    __builtin_amdgcn_s_barrier();
    __builtin_amdgcn_sched_barrier(0);

    for (int tt = 0; tt < 48; ++tt) {
        const int cb = tt & 1;
        const u16* Abuf = SM + cb * 16384;
        const u16* Bbuf = SM + 32768 + cb * 16384;

        bf16x8 bf[4][2];
        #pragma unroll
        for (int n = 0; n < 4; ++n)
            #pragma unroll
            for (int ks = 0; ks < 2; ++ks) {
                const int r = wc * 64 + n * 16 + m16;
                bf[n][ks] = *(const bf16x8*)&Bbuf[r * 64 + (((ks * 4 + g8) ^ (r & 7)) << 3)];
            }
        __builtin_amdgcn_s_setprio(1);
        #pragma unroll
        for (int m = 0; m < 8; ++m) {
            const int r = wr * 128 + m * 16 + m16;
            bf16x8 a0 = *(const bf16x8*)&Abuf[r * 64 + ((g8 ^ (r & 7)) << 3)];
            bf16x8 a1 = *(const bf16x8*)&Abuf[r * 64 + (((4 + g8) ^ (r & 7)) << 3)];
            #pragma unroll
            for (int n = 0; n < 4; ++n) {
                acc[m][n] = __builtin_amdgcn_mfma_f32_16x16x32_bf16(a0, bf[n][0], acc[m][n], 0, 0, 0);
                acc[m][n] = __builtin_amdgcn_mfma_f32_16x16x32_bf16(a1, bf[n][1], acc[m][n], 0, 0, 0);
            }
        }
        __builtin_amdgcn_s_setprio(0);

        __builtin_amdgcn_sched_barrier(0);
        __builtin_amdgcn_s_barrier();      // all waves done reading buf cb
        __builtin_amdgcn_sched_barrier(0);
        if (tt + 2 < 48) {
            STAGE(tt + 2, cb);
            __builtin_amdgcn_sched_barrier(0);
            asm volatile("s_waitcnt vmcnt(8)" ::: "memory");  // tile tt+1 landed
        } else {
            asm volatile("s_waitcnt vmcnt(0)" ::: "memory");
        }
        __builtin_amdgcn_sched_barrier(0);
        __builtin_amdgcn_s_barrier();      // tile tt+1 visible to all waves
        __builtin_amdgcn_sched_barrier(0);
    }

    #pragma unroll
    for (int m = 0; m < 8; ++m) {
        const int row0 = bm + wr * 128 + m * 16 + (g8 << 2);
        #pragma unroll
        for (int n = 0; n < 4; ++n) {
            const int col = bn + wc * 64 + n * 16 + m16;
            const float bv = bias[col];
            #pragma unroll
            for (int e = 0; e < 4; ++e)
                C[(size_t)(row0 + e) * N + col] = acc[m][n][e] + bv;
        }
    }
}

// ---------------------------------------------------------------------------
// 128x128 split GEMM (kept for proj: grid 32x8 = 256 blocks = full CU cover).
// ---------------------------------------------------------------------------
__global__ __launch_bounds__(256) void gemm_mfma_split(
    const u16* __restrict__ Ah, const u16* __restrict__ Al,
    const u16* __restrict__ Bh, const u16* __restrict__ Bl,
    const float* __restrict__ bias, float* __restrict__ C,
    int M, int N, int K, int lda, int ldb) {
    __shared__ u16 sAh[128 * 32], sAl[128 * 32], sBh[128 * 32], sBl[128 * 32];

    const int t    = threadIdx.x;
    const int lane = t & 63;
    const int wid  = t >> 6;
    const int wr   = wid >> 1, wc = wid & 1;

    const int nbx = gridDim.x;
    const int nwg = nbx * gridDim.y;
    int bid = blockIdx.y * nbx + blockIdx.x;
    int swz = (bid & 7) * (nwg >> 3) + (bid >> 3);
    const int bn = (swz % nbx) * 128;
    const int bm = (swz / nbx) * 128;

    const int jr    = lane >> 2;
    const int cphys = lane & 3;
    const int m16 = lane & 15, g8 = lane >> 4;

    f32x4 acc[4][4];
    #pragma unroll
    for (int m = 0; m < 4; ++m)
        #pragma unroll
        for (int n = 0; n < 4; ++n) {
            f32x4 z = {0.0f, 0.0f, 0.0f, 0.0f};
            acc[m][n] = z;
        }

    for (int k0 = 0; k0 < K; k0 += 32) {
        __syncthreads();
        #pragma unroll
        for (int jj = 0; jj < 2; ++jj) {
            const int j = wid * 2 + jj;
            const int r = (j << 4) + jr;
            const int cl = cphys ^ (r & 3);
            const size_t ga = ((size_t)(bm + r) * lda + k0 + (cl << 3)) * 2;
            const size_t gb = ((size_t)(bn + r) * ldb + k0 + (cl << 3)) * 2;
            const unsigned ldso = (unsigned)(j << 10);
            __builtin_amdgcn_global_load_lds(
                (const __attribute__((address_space(1))) void*)((const char*)Ah + ga),
                (__attribute__((address_space(3))) void*)((char*)sAh + ldso), 16, 0, 0);
            __builtin_amdgcn_global_load_lds(
                (const __attribute__((address_space(1))) void*)((const char*)Al + ga),
                (__attribute__((address_space(3))) void*)((char*)sAl + ldso), 16, 0, 0);
            __builtin_amdgcn_global_load_lds(
                (const __attribute__((address_space(1))) void*)((const char*)Bh + gb),
                (__attribute__((address_space(3))) void*)((char*)sBh + ldso), 16, 0, 0);
            __builtin_amdgcn_global_load_lds(
                (const __attribute__((address_space(1))) void*)((const char*)Bl + gb),
                (__attribute__((address_space(3))) void*)((char*)sBl + ldso), 16, 0, 0);
        }
        __syncthreads();

        bf16x8 ah[4], al[4], bh[4], bl[4];
        #pragma unroll
        for (int m = 0; m < 4; ++m) {
            const int r = wr * 64 + m * 16 + m16;
            const int off = (r << 5) + ((g8 ^ (m16 & 3)) << 3);
            ah[m] = *(const bf16x8*)&sAh[off];
            al[m] = *(const bf16x8*)&sAl[off];
        }
        #pragma unroll
        for (int n = 0; n < 4; ++n) {
            const int r = wc * 64 + n * 16 + m16;
            const int off = (r << 5) + ((g8 ^ (m16 & 3)) << 3);
            bh[n] = *(const bf16x8*)&sBh[off];
            bl[n] = *(const bf16x8*)&sBl[off];
        }
        #pragma unroll
        for (int m = 0; m < 4; ++m)
            #pragma unroll
            for (int n = 0; n < 4; ++n) {
                acc[m][n] = __builtin_amdgcn_mfma_f32_16x16x32_bf16(ah[m], bh[n], acc[m][n], 0, 0, 0);
                acc[m][n] = __builtin_amdgcn_mfma_f32_16x16x32_bf16(al[m], bh[n], acc[m][n], 0, 0, 0);
                acc[m][n] = __builtin_amdgcn_mfma_f32_16x16x32_bf16(ah[m], bl[n], acc[m][n], 0, 0, 0);
            }
    }

    #pragma unroll
    for (int m = 0; m < 4; ++m) {
        const int row0 = bm + wr * 64 + m * 16 + (g8 << 2);
        #pragma unroll
        for (int n = 0; n < 4; ++n) {
            const int col = bn + wc * 64 + n * 16 + m16;
            const float bv = bias[col];
            #pragma unroll
            for (int e = 0; e < 4; ++e)
                C[(size_t)(row0 + e) * N + col] = acc[m][n][e] + bv;
        }
    }
}

// ---------------------------------------------------------------------------
// MFMA flash attention (unchanged from round 5 — verified).
// ---------------------------------------------------------------------------
__global__ __launch_bounds__(256) void attn_mfma(const float* __restrict__ qkv,
                                                 const u16* __restrict__ Kh,
                                                 const u16* __restrict__ Kl,
                                                 const u16* __restrict__ Vth,
                                                 const u16* __restrict__ Vtl,
                                                 u16* __restrict__ att) {
    __shared__ __align__(16) u16 SM[32768];  // 64 KB

    const int t    = threadIdx.x;
    const int lane = t & 63;
    const int wv   = t >> 6;
    const int m16  = lane & 15, g8 = lane >> 4;

    const int bid  = blockIdx.x;
    const int work = (bid & 7) * 128 + (bid >> 3);
    const int qt = work & 15;
    const int bh = work >> 4;
    const int h  = bh & 15;
    const int b  = bh >> 4;
    const int q0 = qt * 64;

    const int srow = lane >> 3;
    const int scl  = (lane & 7) ^ srow;
    const size_t kvrow0 = (size_t)bh << 16;

    auto stageK = [&](int kt) {
        const int kb = kt * 64;
        #pragma unroll
        for (int issue = 0; issue < 2; ++issue) {
            const int rloc = (issue * 4 + wv) * 8 + srow;
            const size_t go = (kvrow0 + (size_t)(kb + rloc) * 64 + scl * 8) * 2;
            const unsigned lo = (unsigned)((issue * 4 + wv) * 1024);
            __builtin_amdgcn_global_load_lds(
                (const __attribute__((address_space(1))) void*)((const char*)Kh + go),
                (__attribute__((address_space(3))) void*)((char*)SM + lo), 16, 0, 0);
            __builtin_amdgcn_global_load_lds(
                (const __attribute__((address_space(1))) void*)((const char*)Kl + go),
                (__attribute__((address_space(3))) void*)((char*)SM + 8192 + lo), 16, 0, 0);
        }
    };
    auto stageV = [&](int kt, int bsel) {
        const int kb = kt * 64;
        #pragma unroll
        for (int issue = 0; issue < 2; ++issue) {
            const int rloc = (issue * 4 + wv) * 8 + srow;
            const size_t go = (kvrow0 + (size_t)rloc * 1024 + kb + scl * 8) * 2;
            const unsigned lo = (unsigned)(16384 + bsel * 16384 + (issue * 4 + wv) * 1024);
            __builtin_amdgcn_global_load_lds(
                (const __attribute__((address_space(1))) void*)((const char*)Vth + go),
                (__attribute__((address_space(3))) void*)((char*)SM + lo), 16, 0, 0);
            __builtin_amdgcn_global_load_lds(
                (const __attribute__((address_space(1))) void*)((const char*)Vtl + go),
                (__attribute__((address_space(3))) void*)((char*)SM + 8192 + lo), 16, 0, 0);
        }
    };

    bf16x8 qh[2], ql[2];
    {
        const float* qrow = qkv + (size_t)(b * T_SEQ + q0 + wv * 16 + m16) * C3 + h * HD;
        #pragma unroll
        for (int ds = 0; ds < 2; ++ds) {
            float4 a = *(const float4*)&qrow[ds * 32 + g8 * 8];
            float4 c = *(const float4*)&qrow[ds * 32 + g8 * 8 + 4];
            float q8[8] = {a.x, a.y, a.z, a.w, c.x, c.y, c.z, c.w};
            B8 hh, ll;
            #pragma unroll
            for (int j = 0; j < 8; ++j) {
                u16 hi, lo;
                split_bf16(q8[j] * 0.125f, hi, lo);
                hh.u[j] = hi; ll.u[j] = lo;
            }
            qh[ds] = hh.v; ql[ds] = ll.v;
        }
    }

    f32x4 acc_o[4];
    #pragma unroll
    for (int i = 0; i < 4; ++i) { f32x4 z = {0, 0, 0, 0}; acc_o[i] = z; }
    float m_run = -INFINITY, l_run = 0.0f;

    u16* Phw = SM + 24576 + wv * 1024;
    u16* Plw = SM + 28672 + wv * 1024;

    stageK(0);
    stageV(0, 0);
    asm volatile("s_waitcnt vmcnt(0)" ::: "memory");
    __builtin_amdgcn_s_barrier();
    __builtin_amdgcn_sched_barrier(0);

    int vsel = 0;
    for (int kt = 0; kt < 16; ++kt) {
        f32x4 accs[4];
        #pragma unroll
        for (int i = 0; i < 4; ++i) { f32x4 z = {0, 0, 0, 0}; accs[i] = z; }
        #pragma unroll
        for (int ds = 0; ds < 2; ++ds) {
            #pragma unroll
            for (int sub = 0; sub < 4; ++sub) {
                const int row = sub * 16 + m16;
                const int idx = row * 64 + ((((ds * 4 + g8)) ^ (m16 & 7)) << 3);
                bf16x8 kh = *(const bf16x8*)&SM[idx];
                bf16x8 kl = *(const bf16x8*)&SM[4096 + idx];
                accs[sub] = __builtin_amdgcn_mfma_f32_16x16x32_bf16(kh, qh[ds], accs[sub], 0, 0, 0);
                accs[sub] = __builtin_amdgcn_mfma_f32_16x16x32_bf16(kl, qh[ds], accs[sub], 0, 0, 0);
                accs[sub] = __builtin_amdgcn_mfma_f32_16x16x32_bf16(kh, ql[ds], accs[sub], 0, 0, 0);
            }
        }

        __builtin_amdgcn_sched_barrier(0);
        __builtin_amdgcn_s_barrier();
        __builtin_amdgcn_sched_barrier(0);
        if (kt < 15) { stageK(kt + 1); stageV(kt + 1, vsel ^ 1); }

        float mt = accs[0][0];
        #pragma unroll
        for (int sub = 0; sub < 4; ++sub)
            #pragma unroll
            for (int e = 0; e < 4; ++e) mt = fmaxf(mt, accs[sub][e]);
        mt = fmaxf(mt, __shfl_xor(mt, 16));
        mt = fmaxf(mt, __shfl_xor(mt, 32));
        const float mnew = fmaxf(m_run, mt);
        const float fsc = __expf(m_run - mnew);
        float p[4][4];
        float ts = 0.0f;
        #pragma unroll
        for (int sub = 0; sub < 4; ++sub)
            #pragma unroll
            for (int e = 0; e < 4; ++e) {
                p[sub][e] = __expf(accs[sub][e] - mnew);
                ts += p[sub][e];
            }
        ts += __shfl_xor(ts, 16);
        ts += __shfl_xor(ts, 32);
        l_run = l_run * fsc + ts;
        m_run = mnew;
        #pragma unroll
        for (int d = 0; d < 4; ++d)
            #pragma unroll
            for (int e = 0; e < 4; ++e) acc_o[d][e] *= fsc;

        #pragma unroll
        for (int sub = 0; sub < 4; ++sub)
            #pragma unroll
            for (int pp = 0; pp < 2; ++pp) {
                float p0 = p[sub][2 * pp], p1 = p[sub][2 * pp + 1];
                u16 h0, l0, h1, l1;
                split_bf16(p0, h0, l0);
                split_bf16(p1, h1, l1);
                unsigned hw = (unsigned)h0 | ((unsigned)h1 << 16);
                unsigned lw = (unsigned)l0 | ((unsigned)l1 << 16);
                const int idx = m16 * 64 + (((2 * sub + (g8 >> 1)) ^ (m16 & 7)) << 3)
                                + 4 * (g8 & 1) + 2 * pp;
                *(unsigned*)&Phw[idx] = hw;
                *(unsigned*)&Plw[idx] = lw;
            }

        bf16x8 pfh[2], pfl[2];
        #pragma unroll
        for (int ks = 0; ks < 2; ++ks) {
            const int idx = m16 * 64 + ((((ks * 4 + g8)) ^ (m16 & 7)) << 3);
            pfh[ks] = *(const bf16x8*)&Phw[idx];
            pfl[ks] = *(const bf16x8*)&Plw[idx];
        }

        const int vb = 8192 + vsel * 8192;
        #pragma unroll
        for (int dsub = 0; dsub < 4; ++dsub) {
            #pragma unroll
            for (int ks = 0; ks < 2; ++ks) {
                const int vrow = dsub * 16 + m16;
                const int vidx = vb + vrow * 64 + ((((ks * 4 + g8)) ^ (m16 & 7)) << 3);
                bf16x8 vh = *(const bf16x8*)&SM[vidx];
                bf16x8 vl = *(const bf16x8*)&SM[4096 + vidx];
                acc_o[dsub] = __builtin_amdgcn_mfma_f32_16x16x32_bf16(vh, pfh[ks], acc_o[dsub], 0, 0, 0);
                acc_o[dsub] = __builtin_amdgcn_mfma_f32_16x16x32_bf16(vh, pfl[ks], acc_o[dsub], 0, 0, 0);
                acc_o[dsub] = __builtin_amdgcn_mfma_f32_16x16x32_bf16(vl, pfh[ks], acc_o[dsub], 0, 0, 0);
            }
        }

        __builtin_amdgcn_sched_barrier(0);
        asm volatile("s_waitcnt vmcnt(0)" ::: "memory");
        __builtin_amdgcn_s_barrier();
        __builtin_amdgcn_sched_barrier(0);
        vsel ^= 1;
    }

    const float linv = 1.0f / l_run;
    #pragma unroll
    for (int dsub = 0; dsub < 4; ++dsub)
        #pragma unroll
        for (int pp = 0; pp < 2; ++pp) {
            float o0 = acc_o[dsub][2 * pp] * linv;
            float o1 = acc_o[dsub][2 * pp + 1] * linv;
            u16 h0, l0, h1, l1;
            split_bf16(o0, h0, l0);
            split_bf16(o1, h1, l1);
            unsigned hw = (unsigned)h0 | ((unsigned)h1 << 16);
            unsigned lw = (unsigned)l0 | ((unsigned)l1 << 16);
            const int idx = m16 * 64 + (((2 * dsub + (g8 >> 1)) ^ (m16 & 7)) << 3)
                            + 4 * (g8 & 1) + 2 * pp;
            *(unsigned*)&Phw[idx] = hw;
            *(unsigned*)&Plw[idx] = lw;
        }
    __syncthreads();
    #pragma unroll
    for (int i = 0; i < 2; ++i) {
        int s = t + 256 * i;
        int q_l = s >> 3, dg8 = s & 7;
        const int idx = q_l * 64 + ((dg8 ^ (q_l & 7)) << 3);
        bf16x8 oh = *(const bf16x8*)&SM[24576 + idx];
        bf16x8 ol = *(const bf16x8*)&SM[28672 + idx];
        size_t off = (size_t)(b * T_SEQ + q0 + q_l) * 6144 + 2048 + h * HD + dg8 * 8;
        *(bf16x8*)&att[off] = oh;
        *(bf16x8*)&att[off + 1024] = ol;
    }
}

// ---------------------------------------------------------------------------
extern "C" void kernel_launch(void* const* d_in, const int* in_sizes, int n_in,
                              void* d_out, int out_size, void* d_ws, size_t ws_size,
                              hipStream_t stream) {
    const float* x      = (const float*)d_in[0];
    const float* norm_g = (const float*)d_in[1];
    const float* norm_b = (const float*)d_in[2];
    const float* qkv_w  = (const float*)d_in[3];
    const float* qkv_b  = (const float*)d_in[4];
    const float* qln_g  = (const float*)d_in[5];
    const float* qln_b  = (const float*)d_in[6];
    const float* kln_g  = (const float*)d_in[7];
    const float* kln_b  = (const float*)d_in[8];
    const float* proj_w = (const float*)d_in[9];
    const float* proj_b = (const float*)d_in[10];
    float* out = (float*)d_out;

    char* w = (char*)d_ws;
    float* qkv    = (float*)w;
    u16* qkv_u16  = (u16*)w;
    u16* xn_hi    = (u16*)(w + 50331648);
    u16* xn_lo    = (u16*)(w + 58720256);
    u16* wq_hi    = (u16*)(w + 67108864);
    u16* wq_lo    = (u16*)(w + 73400320);
    u16* Kh       = xn_hi;
    u16* Kl       = xn_lo;
    u16* Vth      = (u16*)(w + 67108864);
    u16* Vtl      = (u16*)(w + 75497472);
    u16* pw_hi    = qkv_u16 + 4096;  // overlay qkv V-region, stride 6144
    u16* pw_lo    = qkv_u16 + 5120;
    u16* att_hi   = qkv_u16 + 2048;  // overlay qkv K-region, stride 6144
    u16* att_lo   = qkv_u16 + 3072;

    const int rows = NB * T_SEQ;  // 4096

    ln_split_kernel<<<rows, 256, 0, stream>>>(x, xn_hi, xn_lo, norm_g, norm_b);
    wsplit_t<<<dim3(C3 / 64, C_DIM / 64), 256, 0, stream>>>(qkv_w, wq_hi, wq_lo, C_DIM, C3, 1024);
    gemm256_mfma_split<<<dim3(C3 / 256, rows / 256), 512, 0, stream>>>(
        xn_hi, xn_lo, wq_hi, wq_lo, qkv_b, qkv, C3, 1024, 1024);
    ln_qk_kernel<<<2 * rows, 256, 0, stream>>>(qkv, qln_g, qln_b, kln_g, kln_b, Kh, Kl);
    vsplit_t<<<1024, 256, 0, stream>>>(qkv, Vth, Vtl);
    wsplit_t<<<dim3(C_DIM / 64, C_DIM / 64), 256, 0, stream>>>(proj_w, pw_hi, pw_lo, C_DIM, C_DIM, 6144);
    attn_mfma<<<1024, 256, 0, stream>>>(qkv, Kh, Kl, Vth, Vtl, qkv_u16);
    gemm_mfma_split<<<dim3(C_DIM / 128, rows / 128), 256, 0, stream>>>(
        att_hi, att_lo, pw_hi, pw_lo, proj_b, out, rows, C_DIM, C_DIM, 6144, 6144);
}